// Round 11
// baseline (1045.427 us; speedup 1.0000x reference)
//
#include <hip/hip_runtime.h>

// LightGCN via CSR build + bf16-table pure-gather layers + fused epilogue.
// E16 = bf16(emb); X1 = G(E16); X2 = G(X1); out = 0.25*(emb + X1 + X2 + G(X2))
// G(x)[c] = sum_{e: col[e]=c} w[e] * x[row[e]].  Accumulation fp32.
// Gather kernels use explicit two-phase batches (loads | sched_barrier | fmas)
// to force B-deep memory-level parallelism.

#define NNODES   500000
#define DIMV     64
#define NEDGE    1250000
#define NELEM    (NNODES * DIMV)          // 32,000,000
#define NELEM4   (NELEM / 4)
#define GRP      8                        // nodes per wave

#define SCAN_BLK   256
#define SCAN_ITEMS 8
#define SCAN_CHUNK (SCAN_BLK * SCAN_ITEMS)              // 2048
#define NB1 ((NNODES + SCAN_CHUNK - 1) / SCAN_CHUNK)    // 245 (<= 256)

// bf16 helpers (RNE, no NaN inputs here)
static __device__ __forceinline__ unsigned short f2bf(float f) {
    unsigned u = __float_as_uint(f);
    unsigned r = (u + 0x7fffu + ((u >> 16) & 1u)) >> 16;
    return (unsigned short)r;
}
static __device__ __forceinline__ float bf2f(unsigned short h) {
    return __uint_as_float((unsigned)h << 16);
}

// ======================= emb -> bf16 copy =======================
__global__ __launch_bounds__(256) void lgcn_cvt(
    const float4* __restrict__ emb4, unsigned long long* __restrict__ dst)
{
    int i = blockIdx.x * blockDim.x + threadIdx.x;
    int stride = gridDim.x * blockDim.x;
    for (; i < NELEM4; i += stride) {
        float4 v = emb4[i];
        unsigned lo = (unsigned)f2bf(v.x) | ((unsigned)f2bf(v.y) << 16);
        unsigned hi = (unsigned)f2bf(v.z) | ((unsigned)f2bf(v.w) << 16);
        unsigned long long o = (unsigned long long)lo | ((unsigned long long)hi << 32);
        __builtin_nontemporal_store(o, &dst[i]);
    }
}

// ======================= CSR build =======================

__global__ __launch_bounds__(256) void lgcn_zero_cnt(int* __restrict__ cnt)
{
    int i = blockIdx.x * blockDim.x + threadIdx.x;
    int stride = gridDim.x * blockDim.x;
    for (; i < NNODES; i += stride) cnt[i] = 0;
}

__global__ __launch_bounds__(256) void lgcn_hist(
    const int* __restrict__ col, int* __restrict__ cnt)
{
    int e = blockIdx.x * blockDim.x + threadIdx.x;
    if (e >= NEDGE) return;
    int c = col[e];
    if ((unsigned)c >= NNODES) return;       // insurance; never triggers
    atomicAdd(&cnt[c], 1);
}

__global__ __launch_bounds__(SCAN_BLK) void lgcn_scan1(
    const int* __restrict__ cnt, int* __restrict__ startv, int* __restrict__ bsum)
{
    __shared__ int sh[SCAN_BLK];
    int b = blockIdx.x;
    int base = b * SCAN_CHUNK;
    int tid = threadIdx.x;
    int v[SCAN_ITEMS];
    int local = 0;
    #pragma unroll
    for (int k = 0; k < SCAN_ITEMS; ++k) {
        int idx = base + tid * SCAN_ITEMS + k;
        v[k] = (idx < NNODES) ? cnt[idx] : 0;
        local += v[k];
    }
    sh[tid] = local;
    __syncthreads();
    for (int off = 1; off < SCAN_BLK; off <<= 1) {
        int x = (tid >= off) ? sh[tid - off] : 0;
        __syncthreads();
        sh[tid] += x;
        __syncthreads();
    }
    int run = (tid == 0) ? 0 : sh[tid - 1];
    if (tid == SCAN_BLK - 1) bsum[b] = sh[tid];
    #pragma unroll
    for (int k = 0; k < SCAN_ITEMS; ++k) {
        int idx = base + tid * SCAN_ITEMS + k;
        if (idx < NNODES) startv[idx] = run;
        run += v[k];
    }
}

__global__ __launch_bounds__(SCAN_BLK) void lgcn_scan2(int* __restrict__ bsum)
{
    __shared__ int sh[SCAN_BLK];
    int tid = threadIdx.x;
    sh[tid] = (tid < NB1) ? bsum[tid] : 0;
    __syncthreads();
    for (int off = 1; off < SCAN_BLK; off <<= 1) {
        int x = (tid >= off) ? sh[tid - off] : 0;
        __syncthreads();
        sh[tid] += x;
        __syncthreads();
    }
    if (tid < NB1) bsum[tid] = (tid == 0) ? 0 : sh[tid - 1];
}

__global__ __launch_bounds__(256) void lgcn_scan3(
    int* __restrict__ startv, int* __restrict__ cursor, const int* __restrict__ bsum)
{
    int i = blockIdx.x * blockDim.x + threadIdx.x;
    if (i < NNODES) {
        int s = startv[i] + bsum[i / SCAN_CHUNK];
        startv[i] = s;
        cursor[i] = s;
    }
    if (i == 0) startv[NNODES] = NEDGE;
}

__global__ __launch_bounds__(256) void lgcn_fill(
    const int* __restrict__ row, const int* __restrict__ col,
    const float* __restrict__ w, int* __restrict__ cursor, int2* __restrict__ pairs)
{
    int e = blockIdx.x * blockDim.x + threadIdx.x;
    if (e >= NEDGE) return;
    int c = col[e];
    if ((unsigned)c >= NNODES) return;       // must match lgcn_hist's guard
    int r = row[e];
    float wt = w[e];
    if ((unsigned)r >= NNODES) { r = 0; wt = 0.f; }   // insurance
    int p = atomicAdd(&cursor[c], 1);
    pairs[p] = make_int2(r, __float_as_int(wt));
}

// ======================= gather: 8 nodes / wave, bf16 src =======================
// Two-phase batches: issue B independent gathers, sched_barrier(0), then
// weight-shuffle + routed fp32 accumulate. Forces B-deep MLP.
// MODE 0/1: xout16[group] = bf16(gather sums)
// MODE 2:   outp[group]   = 0.25 * (emb + x1 + x2 + gather sums)   (fp32 out)
template<int MODE>
__global__ __launch_bounds__(256) void lgcn_gather8(
    const unsigned short* __restrict__ src16, unsigned short* __restrict__ xout16,
    const float* __restrict__ emb, const unsigned short* __restrict__ x1,
    const unsigned short* __restrict__ x2, float* __restrict__ outp,
    const int2* __restrict__ pairs, const int* __restrict__ startv)
{
    constexpr int B = (MODE == 2) ? 16 : 32;   // forced-MLP batch depth

    int t = blockIdx.x * blockDim.x + threadIdx.x;
    int wid = t >> 6;               // one wave per GRP nodes
    int lane = t & 63;              // one lane per dim
    int n0 = wid * GRP;
    if (n0 >= NNODES) return;

    // lane-parallel startv fetch: startv[n0 .. n0+GRP]
    int sv = (lane <= GRP) ? startv[n0 + lane] : 0;
    const int s0   = __shfl(sv, 0);
    const int b1   = __shfl(sv, 1) - s0;
    const int b2   = __shfl(sv, 2) - s0;
    const int b3   = __shfl(sv, 3) - s0;
    const int b4   = __shfl(sv, 4) - s0;
    const int b5   = __shfl(sv, 5) - s0;
    const int b6   = __shfl(sv, 6) - s0;
    const int b7   = __shfl(sv, 7) - s0;
    const int tote = __shfl(sv, 8) - s0;

    const size_t o0 = (size_t)n0 * DIMV + lane;

    // MODE 2: independent epilogue stream loads issue up front (nontemporal)
    float ee[8], p1[8], p2[8];
    if (MODE == 2) {
        #pragma unroll
        for (int i = 0; i < 8; ++i) {
            ee[i] = __builtin_nontemporal_load(&emb[o0 + 64 * i]);
            p1[i] = bf2f(__builtin_nontemporal_load(&x1[o0 + 64 * i]));
            p2[i] = bf2f(__builtin_nontemporal_load(&x2[o0 + 64 * i]));
        }
    }

    float m[8] = {0.f, 0.f, 0.f, 0.f, 0.f, 0.f, 0.f, 0.f};

    for (int base = 0; base < tote; base += 64) {
        int chunk = tote - base; if (chunk > 64) chunk = 64;
        int2 mp = (lane < chunk) ? pairs[s0 + base + lane] : make_int2(0, 0);
        for (int j = 0; j < chunk; j += B) {
            float v[B];
            // ---- phase A: issue all B independent gathers ----
            #pragma unroll
            for (int k = 0; k < B; ++k) {
                int jj = j + k;
                if (jj < chunk) {              // wave-uniform predicate
                    int r = __shfl(mp.x, jj);
                    v[k] = bf2f(src16[(size_t)r * DIMV + lane]);
                } else v[k] = 0.f;
            }
            __builtin_amdgcn_sched_barrier(0); // keep loads clustered & live
            // ---- phase B: weights + routed accumulate ----
            #pragma unroll
            for (int k = 0; k < B; ++k) {
                int jj = j + k;
                float wk = (jj < chunk) ? __int_as_float(__shfl(mp.y, jj)) : 0.f;
                int gj = base + jj;            // group-relative edge idx (uniform)
                if      (gj < b1) m[0] = fmaf(wk, v[k], m[0]);
                else if (gj < b2) m[1] = fmaf(wk, v[k], m[1]);
                else if (gj < b3) m[2] = fmaf(wk, v[k], m[2]);
                else if (gj < b4) m[3] = fmaf(wk, v[k], m[3]);
                else if (gj < b5) m[4] = fmaf(wk, v[k], m[4]);
                else if (gj < b6) m[5] = fmaf(wk, v[k], m[5]);
                else if (gj < b7) m[6] = fmaf(wk, v[k], m[6]);
                else              m[7] = fmaf(wk, v[k], m[7]);
            }
        }
    }

    if (MODE == 2) {
        #pragma unroll
        for (int i = 0; i < 8; ++i)
            __builtin_nontemporal_store((ee[i] + p1[i] + p2[i] + m[i]) * 0.25f,
                                        &outp[o0 + 64 * i]);
    } else {
        #pragma unroll
        for (int i = 0; i < 8; ++i)
            __builtin_nontemporal_store(f2bf(m[i]), &xout16[o0 + 64 * i]);
    }
}

// ======================= fallback: atomic scatter path (fp32) =======================

__global__ __launch_bounds__(256) void lgcn_init(
    const float4* __restrict__ emb, float4* __restrict__ acc,
    float4* __restrict__ A, float4* __restrict__ B)
{
    int i = blockIdx.x * blockDim.x + threadIdx.x;
    int stride = gridDim.x * blockDim.x;
    for (; i < NELEM4; i += stride) {
        float4 v = emb[i];
        acc[i] = v;
        A[i]   = v;
        B[i]   = make_float4(0.f, 0.f, 0.f, 0.f);
    }
}

__global__ __launch_bounds__(256) void lgcn_scatter(
    const float* __restrict__ xcur, float* __restrict__ xnext,
    const int* __restrict__ row, const int* __restrict__ col,
    const float* __restrict__ w)
{
    int t = blockIdx.x * blockDim.x + threadIdx.x;
    int e = t >> 4;
    if (e >= NEDGE) return;
    int d = (t & 15) << 2;
    int r = row[e];
    int c = col[e];
    if ((unsigned)r >= NNODES || (unsigned)c >= NNODES) return;
    float wt = w[e];
    const float4 v = *reinterpret_cast<const float4*>(xcur + (size_t)r * DIMV + d);
    float* dst = xnext + (size_t)c * DIMV + d;
    atomicAdd(dst + 0, wt * v.x);
    atomicAdd(dst + 1, wt * v.y);
    atomicAdd(dst + 2, wt * v.z);
    atomicAdd(dst + 3, wt * v.w);
}

__global__ __launch_bounds__(256) void lgcn_addzero(
    float4* __restrict__ acc, const float4* __restrict__ X, float4* __restrict__ Y)
{
    int i = blockIdx.x * blockDim.x + threadIdx.x;
    int stride = gridDim.x * blockDim.x;
    for (; i < NELEM4; i += stride) {
        float4 a = acc[i];
        float4 x = X[i];
        a.x += x.x; a.y += x.y; a.z += x.z; a.w += x.w;
        acc[i] = a;
        Y[i] = make_float4(0.f, 0.f, 0.f, 0.f);
    }
}

__global__ __launch_bounds__(256) void lgcn_final(
    float4* __restrict__ acc, const float4* __restrict__ X)
{
    int i = blockIdx.x * blockDim.x + threadIdx.x;
    int stride = gridDim.x * blockDim.x;
    for (; i < NELEM4; i += stride) {
        float4 a = acc[i];
        float4 x = X[i];
        a.x = (a.x + x.x) * 0.25f;
        a.y = (a.y + x.y) * 0.25f;
        a.z = (a.z + x.z) * 0.25f;
        a.w = (a.w + x.w) * 0.25f;
        acc[i] = a;
    }
}

// ======================= launch =======================

extern "C" void kernel_launch(void* const* d_in, const int* in_sizes, int n_in,
                              void* d_out, int out_size, void* d_ws, size_t ws_size,
                              hipStream_t stream) {
    const float* emb  = (const float*)d_in[0];   // [N, 64] fp32
    const int*   eidx = (const int*)d_in[1];     // [2, E] int32
    const float* ew   = (const float*)d_in[2];   // [E] fp32
    float* acc = (float*)d_out;                  // [N, 64]

    const int* row = eidx;
    const int* col = eidx + NEDGE;

    // workspace layout (bf16 tables): E16, X1, X2 (64 MB each) + CSR
    unsigned short* E16 = (unsigned short*)d_ws;         // NELEM*2
    unsigned short* X1  = E16 + NELEM;                   // NELEM*2
    unsigned short* X2  = X1 + NELEM;                    // NELEM*2  (3*64e6 B, 8-aligned)
    int2*  pairs  = (int2*)(X2 + NELEM);                 // 10e6 B
    int*   startv = (int*)(pairs + NEDGE);               // (N+1)*4
    int*   cursor = startv + (NNODES + 1);               // N*4
    int*   bsum   = cursor + NNODES;                     // NB1*4
    const size_t needed = (size_t)3 * NELEM * 2 + (size_t)NEDGE * 8
                        + ((size_t)NNODES + 1) * 4 + (size_t)NNODES * 4 + (size_t)NB1 * 4;

    const int EDGE_BLOCKS = (NEDGE + 255) / 256;
    const int NODE_BLOCKS = (NNODES + 255) / 256;
    const int G8_BLOCKS   = ((NNODES / GRP) * 64 + 255) / 256;   // 62500 waves

    if (ws_size >= needed) {
        // ---- emb -> bf16 table ----
        lgcn_cvt<<<2048, 256, 0, stream>>>((const float4*)emb, (unsigned long long*)E16);

        // ---- CSR build ----
        lgcn_zero_cnt<<<1954, 256, 0, stream>>>(cursor);
        lgcn_hist<<<EDGE_BLOCKS, 256, 0, stream>>>(col, cursor);
        lgcn_scan1<<<NB1, SCAN_BLK, 0, stream>>>(cursor, startv, bsum);
        lgcn_scan2<<<1, SCAN_BLK, 0, stream>>>(bsum);
        lgcn_scan3<<<NODE_BLOCKS, 256, 0, stream>>>(startv, cursor, bsum);
        lgcn_fill<<<EDGE_BLOCKS, 256, 0, stream>>>(row, col, ew, cursor, pairs);

        // ---- layers ----
        lgcn_gather8<0><<<G8_BLOCKS, 256, 0, stream>>>(
            E16, X1, nullptr, nullptr, nullptr, nullptr, pairs, startv);
        lgcn_gather8<1><<<G8_BLOCKS, 256, 0, stream>>>(
            X1, X2, nullptr, nullptr, nullptr, nullptr, pairs, startv);
        lgcn_gather8<2><<<G8_BLOCKS, 256, 0, stream>>>(
            X2, nullptr, emb, X1, X2, acc, pairs, startv);
    } else {
        // ---- fallback: proven fp32 atomic-scatter path ----
        float* A = (float*)d_ws;
        float* B = A + NELEM;
        const int SC_BLOCKS = (NEDGE * 16 + 255) / 256;
        lgcn_init<<<2048, 256, 0, stream>>>(
            (const float4*)emb, (float4*)acc, (float4*)A, (float4*)B);
        lgcn_scatter<<<SC_BLOCKS, 256, 0, stream>>>(A, B, row, col, ew);
        lgcn_addzero<<<2048, 256, 0, stream>>>((float4*)acc, (const float4*)B, (float4*)A);
        lgcn_scatter<<<SC_BLOCKS, 256, 0, stream>>>(B, A, row, col, ew);
        lgcn_addzero<<<2048, 256, 0, stream>>>((float4*)acc, (const float4*)A, (float4*)B);
        lgcn_scatter<<<SC_BLOCKS, 256, 0, stream>>>(A, B, row, col, ew);
        lgcn_final<<<2048, 256, 0, stream>>>((float4*)acc, (const float4*)B);
    }
}

// Round 12
// 860.632 us; speedup vs baseline: 1.2147x; 1.2147x over previous
//
#include <hip/hip_runtime.h>

// LightGCN via CSR build + double-buffered high-MLP gather layers.
// X1 = G(emb); X2 = G(X1); out = 0.25*(emb + X1 + X2 + G(X2))
// G(x)[c] = sum_{e: col[e]=c} w[e] * x[row[e]].  fp32 accumulation.
// X1/X2 stored bf16. Gathers double-buffered 16-deep (dataflow MLP, no fences).

#define NNODES   500000
#define DIMV     64
#define NEDGE    1250000
#define NELEM    (NNODES * DIMV)          // 32,000,000
#define NELEM4   (NELEM / 4)
#define GRP      8                        // nodes per wave

#define SCAN_BLK   256
#define SCAN_ITEMS 8
#define SCAN_CHUNK (SCAN_BLK * SCAN_ITEMS)              // 2048
#define NB1 ((NNODES + SCAN_CHUNK - 1) / SCAN_CHUNK)    // 245 (<= 256)

// bf16 helpers (RNE)
static __device__ __forceinline__ unsigned short f2bf(float f) {
    unsigned u = __float_as_uint(f);
    unsigned r = (u + 0x7fffu + ((u >> 16) & 1u)) >> 16;
    return (unsigned short)r;
}
static __device__ __forceinline__ float bf2f(unsigned short h) {
    return __uint_as_float((unsigned)h << 16);
}

// ======================= CSR build =======================

__global__ __launch_bounds__(256) void lgcn_hist(
    const int* __restrict__ col, int* __restrict__ cnt)
{
    int e = blockIdx.x * blockDim.x + threadIdx.x;
    if (e >= NEDGE) return;
    int c = col[e];
    if ((unsigned)c >= NNODES) return;       // insurance; never triggers
    atomicAdd(&cnt[c], 1);
}

__global__ __launch_bounds__(SCAN_BLK) void lgcn_scan1(
    const int* __restrict__ cnt, int* __restrict__ startv, int* __restrict__ bsum)
{
    __shared__ int sh[SCAN_BLK];
    int b = blockIdx.x;
    int base = b * SCAN_CHUNK;
    int tid = threadIdx.x;
    int v[SCAN_ITEMS];
    int local = 0;
    #pragma unroll
    for (int k = 0; k < SCAN_ITEMS; ++k) {
        int idx = base + tid * SCAN_ITEMS + k;
        v[k] = (idx < NNODES) ? cnt[idx] : 0;
        local += v[k];
    }
    sh[tid] = local;
    __syncthreads();
    for (int off = 1; off < SCAN_BLK; off <<= 1) {
        int x = (tid >= off) ? sh[tid - off] : 0;
        __syncthreads();
        sh[tid] += x;
        __syncthreads();
    }
    int run = (tid == 0) ? 0 : sh[tid - 1];
    if (tid == SCAN_BLK - 1) bsum[b] = sh[tid];
    #pragma unroll
    for (int k = 0; k < SCAN_ITEMS; ++k) {
        int idx = base + tid * SCAN_ITEMS + k;
        if (idx < NNODES) startv[idx] = run;
        run += v[k];
    }
}

__global__ __launch_bounds__(SCAN_BLK) void lgcn_scan2(int* __restrict__ bsum)
{
    __shared__ int sh[SCAN_BLK];
    int tid = threadIdx.x;
    sh[tid] = (tid < NB1) ? bsum[tid] : 0;
    __syncthreads();
    for (int off = 1; off < SCAN_BLK; off <<= 1) {
        int x = (tid >= off) ? sh[tid - off] : 0;
        __syncthreads();
        sh[tid] += x;
        __syncthreads();
    }
    if (tid < NB1) bsum[tid] = (tid == 0) ? 0 : sh[tid - 1];
}

__global__ __launch_bounds__(256) void lgcn_scan3(
    int* __restrict__ startv, int* __restrict__ cursor, const int* __restrict__ bsum)
{
    int i = blockIdx.x * blockDim.x + threadIdx.x;
    if (i < NNODES) {
        int s = startv[i] + bsum[i / SCAN_CHUNK];
        startv[i] = s;
        cursor[i] = s;
    }
    if (i == 0) startv[NNODES] = NEDGE;
}

__global__ __launch_bounds__(256) void lgcn_fill(
    const int* __restrict__ row, const int* __restrict__ col,
    const float* __restrict__ w, int* __restrict__ cursor, int2* __restrict__ pairs)
{
    int e = blockIdx.x * blockDim.x + threadIdx.x;
    if (e >= NEDGE) return;
    int c = col[e];
    if ((unsigned)c >= NNODES) return;       // must match lgcn_hist's guard
    int r = row[e];
    float wt = w[e];
    if ((unsigned)r >= NNODES) { r = 0; wt = 0.f; }   // insurance
    int p = atomicAdd(&cursor[c], 1);
    pairs[p] = make_int2(r, __float_as_int(wt));
}

// ======================= gather: 8 nodes / wave, 16-deep dbuf =======================
// MODE 0: src = fp32 emb table;  out X1 bf16
// MODE 1: src = bf16 X1;         out X2 bf16
// MODE 2: src = bf16 X2 + fp32 streams; out fp32 = 0.25*(emb+X1+X2+G)
template<int MODE>
__global__ __launch_bounds__(256, 4) void lgcn_gather8(
    const float* __restrict__ srcf, const unsigned short* __restrict__ src16,
    unsigned short* __restrict__ xout16,
    const float* __restrict__ emb, const unsigned short* __restrict__ x1,
    const unsigned short* __restrict__ x2, float* __restrict__ outp,
    const int2* __restrict__ pairs, const int* __restrict__ startv)
{
    int t = blockIdx.x * blockDim.x + threadIdx.x;
    int wid = t >> 6;               // one wave per GRP nodes
    int lane = t & 63;              // one lane per dim
    int n0 = wid * GRP;
    if (n0 >= NNODES) return;

    // lane-parallel startv fetch: startv[n0 .. n0+GRP]
    int sv = (lane <= GRP) ? startv[n0 + lane] : 0;
    const int s0   = __shfl(sv, 0);
    const int b1   = __shfl(sv, 1) - s0;
    const int b2   = __shfl(sv, 2) - s0;
    const int b3   = __shfl(sv, 3) - s0;
    const int b4   = __shfl(sv, 4) - s0;
    const int b5   = __shfl(sv, 5) - s0;
    const int b6   = __shfl(sv, 6) - s0;
    const int b7   = __shfl(sv, 7) - s0;
    const int tote = __shfl(sv, 8) - s0;

    const size_t o0 = (size_t)n0 * DIMV + lane;

    float m[8] = {0.f, 0.f, 0.f, 0.f, 0.f, 0.f, 0.f, 0.f};

    // 16-gather batch load into named buffer (predicated, all-independent)
#define LOADB(V, JBASE)                                                        \
    _Pragma("unroll")                                                          \
    for (int k = 0; k < 16; ++k) {                                             \
        int jj = (JBASE) + k;                                                  \
        if (jj < chunk) {                                                      \
            int r = __shfl(mp.x, jj);                                          \
            V[k] = (MODE == 0) ? srcf[(size_t)r * DIMV + lane]                 \
                               : bf2f(src16[(size_t)r * DIMV + lane]);         \
        } else V[k] = 0.f;                                                     \
    }

    // consume one batch: weights + routed accumulate (uniform branch chain)
#define CONSB(V, JBASE)                                                        \
    _Pragma("unroll")                                                          \
    for (int k = 0; k < 16; ++k) {                                             \
        int jj = (JBASE) + k;                                                  \
        float wk = (jj < chunk) ? __int_as_float(__shfl(mp.y, jj)) : 0.f;      \
        int gj = base + jj;                                                    \
        if      (gj < b1) m[0] = fmaf(wk, V[k], m[0]);                         \
        else if (gj < b2) m[1] = fmaf(wk, V[k], m[1]);                         \
        else if (gj < b3) m[2] = fmaf(wk, V[k], m[2]);                         \
        else if (gj < b4) m[3] = fmaf(wk, V[k], m[3]);                         \
        else if (gj < b5) m[4] = fmaf(wk, V[k], m[4]);                         \
        else if (gj < b6) m[5] = fmaf(wk, V[k], m[5]);                         \
        else if (gj < b7) m[6] = fmaf(wk, V[k], m[6]);                         \
        else              m[7] = fmaf(wk, V[k], m[7]);                         \
    }

    for (int base = 0; base < tote; base += 64) {
        int chunk = tote - base; if (chunk > 64) chunk = 64;
        int2 mp = (lane < chunk) ? pairs[s0 + base + lane] : make_int2(0, 0);

        float va[16], vb[16];
        LOADB(va, 0)
        int j = 0;
        while (true) {
            // even step: prefetch next into vb, consume va
            if (j + 16 < chunk) { LOADB(vb, j + 16) }
            CONSB(va, j)
            j += 16;
            if (j >= chunk) break;
            // odd step: prefetch next into va, consume vb
            if (j + 16 < chunk) { LOADB(va, j + 16) }
            CONSB(vb, j)
            j += 16;
            if (j >= chunk) break;
        }
    }
#undef LOADB
#undef CONSB

    if (MODE == 2) {
        // streaming epilogue (independent loads; issued post-gather)
        #pragma unroll
        for (int i = 0; i < 8; ++i) {
            float ee = __builtin_nontemporal_load(&emb[o0 + 64 * i]);
            float q1 = bf2f(__builtin_nontemporal_load(&x1[o0 + 64 * i]));
            float q2 = bf2f(__builtin_nontemporal_load(&x2[o0 + 64 * i]));
            __builtin_nontemporal_store((ee + q1 + q2 + m[i]) * 0.25f,
                                        &outp[o0 + 64 * i]);
        }
    } else {
        #pragma unroll
        for (int i = 0; i < 8; ++i)
            __builtin_nontemporal_store(f2bf(m[i]), &xout16[o0 + 64 * i]);
    }
}

// ======================= fallback: atomic scatter path (fp32) =======================

__global__ __launch_bounds__(256) void lgcn_init(
    const float4* __restrict__ emb, float4* __restrict__ acc,
    float4* __restrict__ A, float4* __restrict__ B)
{
    int i = blockIdx.x * blockDim.x + threadIdx.x;
    int stride = gridDim.x * blockDim.x;
    for (; i < NELEM4; i += stride) {
        float4 v = emb[i];
        acc[i] = v;
        A[i]   = v;
        B[i]   = make_float4(0.f, 0.f, 0.f, 0.f);
    }
}

__global__ __launch_bounds__(256) void lgcn_scatter(
    const float* __restrict__ xcur, float* __restrict__ xnext,
    const int* __restrict__ row, const int* __restrict__ col,
    const float* __restrict__ w)
{
    int t = blockIdx.x * blockDim.x + threadIdx.x;
    int e = t >> 4;
    if (e >= NEDGE) return;
    int d = (t & 15) << 2;
    int r = row[e];
    int c = col[e];
    if ((unsigned)r >= NNODES || (unsigned)c >= NNODES) return;
    float wt = w[e];
    const float4 v = *reinterpret_cast<const float4*>(xcur + (size_t)r * DIMV + d);
    float* dst = xnext + (size_t)c * DIMV + d;
    atomicAdd(dst + 0, wt * v.x);
    atomicAdd(dst + 1, wt * v.y);
    atomicAdd(dst + 2, wt * v.z);
    atomicAdd(dst + 3, wt * v.w);
}

__global__ __launch_bounds__(256) void lgcn_addzero(
    float4* __restrict__ acc, const float4* __restrict__ X, float4* __restrict__ Y)
{
    int i = blockIdx.x * blockDim.x + threadIdx.x;
    int stride = gridDim.x * blockDim.x;
    for (; i < NELEM4; i += stride) {
        float4 a = acc[i];
        float4 x = X[i];
        a.x += x.x; a.y += x.y; a.z += x.z; a.w += x.w;
        acc[i] = a;
        Y[i] = make_float4(0.f, 0.f, 0.f, 0.f);
    }
}

__global__ __launch_bounds__(256) void lgcn_final(
    float4* __restrict__ acc, const float4* __restrict__ X)
{
    int i = blockIdx.x * blockDim.x + threadIdx.x;
    int stride = gridDim.x * blockDim.x;
    for (; i < NELEM4; i += stride) {
        float4 a = acc[i];
        float4 x = X[i];
        a.x = (a.x + x.x) * 0.25f;
        a.y = (a.y + x.y) * 0.25f;
        a.z = (a.z + x.z) * 0.25f;
        a.w = (a.w + x.w) * 0.25f;
        acc[i] = a;
    }
}

// ======================= launch =======================

extern "C" void kernel_launch(void* const* d_in, const int* in_sizes, int n_in,
                              void* d_out, int out_size, void* d_ws, size_t ws_size,
                              hipStream_t stream) {
    const float* emb  = (const float*)d_in[0];   // [N, 64] fp32
    const int*   eidx = (const int*)d_in[1];     // [2, E] int32
    const float* ew   = (const float*)d_in[2];   // [E] fp32
    float* acc = (float*)d_out;                  // [N, 64]

    const int* row = eidx;
    const int* col = eidx + NEDGE;

    // workspace: X1, X2 (bf16, 64 MB each) + CSR arrays
    unsigned short* X1  = (unsigned short*)d_ws;         // NELEM*2
    unsigned short* X2  = X1 + NELEM;                    // NELEM*2
    int2*  pairs  = (int2*)(X2 + NELEM);                 // 10e6 B (8-aligned)
    int*   startv = (int*)(pairs + NEDGE);               // (N+1)*4
    int*   cursor = startv + (NNODES + 1);               // N*4
    int*   bsum   = cursor + NNODES;                     // NB1*4
    const size_t needed = (size_t)2 * NELEM * 2 + (size_t)NEDGE * 8
                        + ((size_t)NNODES + 1) * 4 + (size_t)NNODES * 4 + (size_t)NB1 * 4;

    const int EDGE_BLOCKS = (NEDGE + 255) / 256;
    const int NODE_BLOCKS = (NNODES + 255) / 256;
    const int G8_BLOCKS   = ((NNODES / GRP) * 64 + 255) / 256;   // 62500 waves

    if (ws_size >= needed) {
        // ---- CSR build ----
        hipMemsetAsync(cursor, 0, (size_t)NNODES * 4, stream);
        lgcn_hist<<<EDGE_BLOCKS, 256, 0, stream>>>(col, cursor);
        lgcn_scan1<<<NB1, SCAN_BLK, 0, stream>>>(cursor, startv, bsum);
        lgcn_scan2<<<1, SCAN_BLK, 0, stream>>>(bsum);
        lgcn_scan3<<<NODE_BLOCKS, 256, 0, stream>>>(startv, cursor, bsum);
        lgcn_fill<<<EDGE_BLOCKS, 256, 0, stream>>>(row, col, ew, cursor, pairs);

        // ---- layers ----
        lgcn_gather8<0><<<G8_BLOCKS, 256, 0, stream>>>(
            emb, nullptr, X1, nullptr, nullptr, nullptr, nullptr, pairs, startv);
        lgcn_gather8<1><<<G8_BLOCKS, 256, 0, stream>>>(
            nullptr, X1, X2, nullptr, nullptr, nullptr, nullptr, pairs, startv);
        lgcn_gather8<2><<<G8_BLOCKS, 256, 0, stream>>>(
            nullptr, X2, nullptr, emb, X1, X2, acc, pairs, startv);
    } else {
        // ---- fallback: proven fp32 atomic-scatter path ----
        float* A = (float*)d_ws;
        float* B = A + NELEM;
        const int SC_BLOCKS = (NEDGE * 16 + 255) / 256;
        lgcn_init<<<2048, 256, 0, stream>>>(
            (const float4*)emb, (float4*)acc, (float4*)A, (float4*)B);
        lgcn_scatter<<<SC_BLOCKS, 256, 0, stream>>>(A, B, row, col, ew);
        lgcn_addzero<<<2048, 256, 0, stream>>>((float4*)acc, (const float4*)B, (float4*)A);
        lgcn_scatter<<<SC_BLOCKS, 256, 0, stream>>>(B, A, row, col, ew);
        lgcn_addzero<<<2048, 256, 0, stream>>>((float4*)acc, (const float4*)A, (float4*)B);
        lgcn_scatter<<<SC_BLOCKS, 256, 0, stream>>>(A, B, row, col, ew);
        lgcn_final<<<2048, 256, 0, stream>>>((float4*)acc, (const float4*)B);
    }
}

// Round 13
// 446.880 us; speedup vs baseline: 2.3394x; 1.9259x over previous
//
#include <hip/hip_runtime.h>

// LightGCN via CSR build + 16-lanes-per-node gather layers (no routing).
// X1 = G(emb); X2 = G(X1); out = 0.25*(emb + X1 + X2 + G(X2))
// G(x)[c] = sum_{e: col[e]=c} w[e] * x[row[e]].  fp32 accumulation.
// X1/X2 stored bf16. 4 nodes/wave, 16 lanes/node, 4 dims/lane.

#define NNODES   500000
#define DIMV     64
#define NEDGE    1250000
#define NELEM    (NNODES * DIMV)          // 32,000,000
#define NELEM4   (NELEM / 4)

#define SCAN_BLK   256
#define SCAN_ITEMS 8
#define SCAN_CHUNK (SCAN_BLK * SCAN_ITEMS)              // 2048
#define NB1 ((NNODES + SCAN_CHUNK - 1) / SCAN_CHUNK)    // 245 (<= 256)

// bf16 helpers (RNE)
static __device__ __forceinline__ unsigned short f2bf(float f) {
    unsigned u = __float_as_uint(f);
    unsigned r = (u + 0x7fffu + ((u >> 16) & 1u)) >> 16;
    return (unsigned short)r;
}
static __device__ __forceinline__ float bf2f(unsigned short h) {
    return __uint_as_float((unsigned)h << 16);
}

// ======================= CSR build =======================

__global__ __launch_bounds__(256) void lgcn_hist(
    const int* __restrict__ col, int* __restrict__ cnt)
{
    int e = blockIdx.x * blockDim.x + threadIdx.x;
    if (e >= NEDGE) return;
    int c = col[e];
    if ((unsigned)c >= NNODES) return;       // insurance; never triggers
    atomicAdd(&cnt[c], 1);
}

__global__ __launch_bounds__(SCAN_BLK) void lgcn_scan1(
    const int* __restrict__ cnt, int* __restrict__ startv, int* __restrict__ bsum)
{
    __shared__ int sh[SCAN_BLK];
    int b = blockIdx.x;
    int base = b * SCAN_CHUNK;
    int tid = threadIdx.x;
    int v[SCAN_ITEMS];
    int local = 0;
    #pragma unroll
    for (int k = 0; k < SCAN_ITEMS; ++k) {
        int idx = base + tid * SCAN_ITEMS + k;
        v[k] = (idx < NNODES) ? cnt[idx] : 0;
        local += v[k];
    }
    sh[tid] = local;
    __syncthreads();
    for (int off = 1; off < SCAN_BLK; off <<= 1) {
        int x = (tid >= off) ? sh[tid - off] : 0;
        __syncthreads();
        sh[tid] += x;
        __syncthreads();
    }
    int run = (tid == 0) ? 0 : sh[tid - 1];
    if (tid == SCAN_BLK - 1) bsum[b] = sh[tid];
    #pragma unroll
    for (int k = 0; k < SCAN_ITEMS; ++k) {
        int idx = base + tid * SCAN_ITEMS + k;
        if (idx < NNODES) startv[idx] = run;
        run += v[k];
    }
}

__global__ __launch_bounds__(SCAN_BLK) void lgcn_scan2(int* __restrict__ bsum)
{
    __shared__ int sh[SCAN_BLK];
    int tid = threadIdx.x;
    sh[tid] = (tid < NB1) ? bsum[tid] : 0;
    __syncthreads();
    for (int off = 1; off < SCAN_BLK; off <<= 1) {
        int x = (tid >= off) ? sh[tid - off] : 0;
        __syncthreads();
        sh[tid] += x;
        __syncthreads();
    }
    if (tid < NB1) bsum[tid] = (tid == 0) ? 0 : sh[tid - 1];
}

__global__ __launch_bounds__(256) void lgcn_scan3(
    int* __restrict__ startv, int* __restrict__ cursor, const int* __restrict__ bsum)
{
    int i = blockIdx.x * blockDim.x + threadIdx.x;
    if (i < NNODES) {
        int s = startv[i] + bsum[i / SCAN_CHUNK];
        startv[i] = s;
        cursor[i] = s;
    }
    if (i == 0) startv[NNODES] = NEDGE;
}

__global__ __launch_bounds__(256) void lgcn_fill(
    const int* __restrict__ row, const int* __restrict__ col,
    const float* __restrict__ w, int* __restrict__ cursor, int2* __restrict__ pairs)
{
    int e = blockIdx.x * blockDim.x + threadIdx.x;
    if (e >= NEDGE) return;
    int c = col[e];
    if ((unsigned)c >= NNODES) return;       // must match lgcn_hist's guard
    int r = row[e];
    float wt = w[e];
    if ((unsigned)r >= NNODES) { r = 0; wt = 0.f; }   // insurance
    int p = atomicAdd(&cursor[c], 1);
    pairs[p] = make_int2(r, __float_as_int(wt));
}

// ======================= gather: 4 nodes/wave, 16 lanes/node =======================
// Each 16-lane group owns one node; lane sub = 4 consecutive dims.
// No shuffles, no routing: pairs[idx] broadcast-loads within the group,
// padding edges carry w=0. U=8 two-phase batches give ~32 rows in flight/wave.
// MODE 0: src fp32 emb -> X1 bf16;  MODE 1: X1 bf16 -> X2 bf16
// MODE 2: X2 bf16 + streams -> out fp32 = 0.25*(emb+X1+X2+G)
template<int MODE>
__global__ __launch_bounds__(256, 6) void lgcn_gather4(
    const float* __restrict__ srcf, const unsigned short* __restrict__ src16,
    unsigned short* __restrict__ xout16,
    const float* __restrict__ emb, const unsigned short* __restrict__ x1,
    const unsigned short* __restrict__ x2, float* __restrict__ outp,
    const int2* __restrict__ pairs, const int* __restrict__ startv)
{
    constexpr int U = 8;
    int t = blockIdx.x * blockDim.x + threadIdx.x;
    int wid = t >> 6;               // wave id: 4 nodes per wave
    int lane = t & 63;
    int g = lane >> 4;              // node slot in wave (0..3)
    int sub = lane & 15;            // dim quad (dims sub*4 .. sub*4+3)
    int n = wid * 4 + g;
    if (n >= NNODES) return;

    int s = startv[n];              // same addr across 16 lanes -> broadcast
    int e = startv[n + 1];

    float ax = 0.f, ay = 0.f, az = 0.f, aw = 0.f;

    for (int i = s; i < e; i += U) {
        int2 pr[U];
        #pragma unroll
        for (int k = 0; k < U; ++k) {
            int idx = i + k;
            pr[k] = (idx < e) ? pairs[idx] : make_int2(0, 0);
        }
        float vx[U], vy[U], vz[U], vw[U];
        #pragma unroll
        for (int k = 0; k < U; ++k) {
            if (i + k < e) {
                if (MODE == 0) {
                    const float4 rv = *reinterpret_cast<const float4*>(
                        &srcf[(size_t)pr[k].x * DIMV + sub * 4]);
                    vx[k] = rv.x; vy[k] = rv.y; vz[k] = rv.z; vw[k] = rv.w;
                } else {
                    const ushort4 rw = *reinterpret_cast<const ushort4*>(
                        &src16[(size_t)pr[k].x * DIMV + sub * 4]);
                    vx[k] = bf2f(rw.x); vy[k] = bf2f(rw.y);
                    vz[k] = bf2f(rw.z); vw[k] = bf2f(rw.w);
                }
            } else { vx[k] = vy[k] = vz[k] = vw[k] = 0.f; }
        }
        #pragma unroll
        for (int k = 0; k < U; ++k) {
            float wk = __int_as_float(pr[k].y);   // 0 for padding edges
            ax = fmaf(wk, vx[k], ax);
            ay = fmaf(wk, vy[k], ay);
            az = fmaf(wk, vz[k], az);
            aw = fmaf(wk, vw[k], aw);
        }
    }

    const size_t o = (size_t)n * DIMV + sub * 4;
    if (MODE == 2) {
        float4 ev = *reinterpret_cast<const float4*>(&emb[o]);
        unsigned long long u1 =
            __builtin_nontemporal_load(reinterpret_cast<const unsigned long long*>(&x1[o]));
        unsigned long long u2 =
            __builtin_nontemporal_load(reinterpret_cast<const unsigned long long*>(&x2[o]));
        float4 r;
        r.x = (ev.x + bf2f((unsigned short)(u1      )) + bf2f((unsigned short)(u2      )) + ax) * 0.25f;
        r.y = (ev.y + bf2f((unsigned short)(u1 >> 16)) + bf2f((unsigned short)(u2 >> 16)) + ay) * 0.25f;
        r.z = (ev.z + bf2f((unsigned short)(u1 >> 32)) + bf2f((unsigned short)(u2 >> 32)) + az) * 0.25f;
        r.w = (ev.w + bf2f((unsigned short)(u1 >> 48)) + bf2f((unsigned short)(u2 >> 48)) + aw) * 0.25f;
        *reinterpret_cast<float4*>(&outp[o]) = r;
    } else {
        unsigned long long pk =
              (unsigned long long)f2bf(ax)
            | ((unsigned long long)f2bf(ay) << 16)
            | ((unsigned long long)f2bf(az) << 32)
            | ((unsigned long long)f2bf(aw) << 48);
        __builtin_nontemporal_store(pk,
            reinterpret_cast<unsigned long long*>(&xout16[o]));
    }
}

// ======================= fallback: atomic scatter path (fp32) =======================

__global__ __launch_bounds__(256) void lgcn_init(
    const float4* __restrict__ emb, float4* __restrict__ acc,
    float4* __restrict__ A, float4* __restrict__ B)
{
    int i = blockIdx.x * blockDim.x + threadIdx.x;
    int stride = gridDim.x * blockDim.x;
    for (; i < NELEM4; i += stride) {
        float4 v = emb[i];
        acc[i] = v;
        A[i]   = v;
        B[i]   = make_float4(0.f, 0.f, 0.f, 0.f);
    }
}

__global__ __launch_bounds__(256) void lgcn_scatter(
    const float* __restrict__ xcur, float* __restrict__ xnext,
    const int* __restrict__ row, const int* __restrict__ col,
    const float* __restrict__ w)
{
    int t = blockIdx.x * blockDim.x + threadIdx.x;
    int e = t >> 4;
    if (e >= NEDGE) return;
    int d = (t & 15) << 2;
    int r = row[e];
    int c = col[e];
    if ((unsigned)r >= NNODES || (unsigned)c >= NNODES) return;
    float wt = w[e];
    const float4 v = *reinterpret_cast<const float4*>(xcur + (size_t)r * DIMV + d);
    float* dst = xnext + (size_t)c * DIMV + d;
    atomicAdd(dst + 0, wt * v.x);
    atomicAdd(dst + 1, wt * v.y);
    atomicAdd(dst + 2, wt * v.z);
    atomicAdd(dst + 3, wt * v.w);
}

__global__ __launch_bounds__(256) void lgcn_addzero(
    float4* __restrict__ acc, const float4* __restrict__ X, float4* __restrict__ Y)
{
    int i = blockIdx.x * blockDim.x + threadIdx.x;
    int stride = gridDim.x * blockDim.x;
    for (; i < NELEM4; i += stride) {
        float4 a = acc[i];
        float4 x = X[i];
        a.x += x.x; a.y += x.y; a.z += x.z; a.w += x.w;
        acc[i] = a;
        Y[i] = make_float4(0.f, 0.f, 0.f, 0.f);
    }
}

__global__ __launch_bounds__(256) void lgcn_final(
    float4* __restrict__ acc, const float4* __restrict__ X)
{
    int i = blockIdx.x * blockDim.x + threadIdx.x;
    int stride = gridDim.x * blockDim.x;
    for (; i < NELEM4; i += stride) {
        float4 a = acc[i];
        float4 x = X[i];
        a.x = (a.x + x.x) * 0.25f;
        a.y = (a.y + x.y) * 0.25f;
        a.z = (a.z + x.z) * 0.25f;
        a.w = (a.w + x.w) * 0.25f;
        acc[i] = a;
    }
}

// ======================= launch =======================

extern "C" void kernel_launch(void* const* d_in, const int* in_sizes, int n_in,
                              void* d_out, int out_size, void* d_ws, size_t ws_size,
                              hipStream_t stream) {
    const float* emb  = (const float*)d_in[0];   // [N, 64] fp32
    const int*   eidx = (const int*)d_in[1];     // [2, E] int32
    const float* ew   = (const float*)d_in[2];   // [E] fp32
    float* acc = (float*)d_out;                  // [N, 64]

    const int* row = eidx;
    const int* col = eidx + NEDGE;

    // workspace: X1, X2 (bf16, 64 MB each) + CSR arrays
    unsigned short* X1  = (unsigned short*)d_ws;         // NELEM*2
    unsigned short* X2  = X1 + NELEM;                    // NELEM*2
    int2*  pairs  = (int2*)(X2 + NELEM);                 // 10e6 B (8-aligned)
    int*   startv = (int*)(pairs + NEDGE);               // (N+1)*4
    int*   cursor = startv + (NNODES + 1);               // N*4
    int*   bsum   = cursor + NNODES;                     // NB1*4
    const size_t needed = (size_t)2 * NELEM * 2 + (size_t)NEDGE * 8
                        + ((size_t)NNODES + 1) * 4 + (size_t)NNODES * 4 + (size_t)NB1 * 4;

    const int EDGE_BLOCKS = (NEDGE + 255) / 256;
    const int NODE_BLOCKS = (NNODES + 255) / 256;
    const int G4_BLOCKS   = (NNODES * 16 + 255) / 256;   // 4 nodes/wave -> 125K waves

    if (ws_size >= needed) {
        // ---- CSR build ----
        hipMemsetAsync(cursor, 0, (size_t)NNODES * 4, stream);
        lgcn_hist<<<EDGE_BLOCKS, 256, 0, stream>>>(col, cursor);
        lgcn_scan1<<<NB1, SCAN_BLK, 0, stream>>>(cursor, startv, bsum);
        lgcn_scan2<<<1, SCAN_BLK, 0, stream>>>(bsum);
        lgcn_scan3<<<NODE_BLOCKS, 256, 0, stream>>>(startv, cursor, bsum);
        lgcn_fill<<<EDGE_BLOCKS, 256, 0, stream>>>(row, col, ew, cursor, pairs);

        // ---- layers ----
        lgcn_gather4<0><<<G4_BLOCKS, 256, 0, stream>>>(
            emb, nullptr, X1, nullptr, nullptr, nullptr, nullptr, pairs, startv);
        lgcn_gather4<1><<<G4_BLOCKS, 256, 0, stream>>>(
            nullptr, X1, X2, nullptr, nullptr, nullptr, nullptr, pairs, startv);
        lgcn_gather4<2><<<G4_BLOCKS, 256, 0, stream>>>(
            nullptr, X2, nullptr, emb, X1, X2, acc, pairs, startv);
    } else {
        // ---- fallback: proven fp32 atomic-scatter path ----
        float* A = (float*)d_ws;
        float* B = A + NELEM;
        const int SC_BLOCKS = (NEDGE * 16 + 255) / 256;
        lgcn_init<<<2048, 256, 0, stream>>>(
            (const float4*)emb, (float4*)acc, (float4*)A, (float4*)B);
        lgcn_scatter<<<SC_BLOCKS, 256, 0, stream>>>(A, B, row, col, ew);
        lgcn_addzero<<<2048, 256, 0, stream>>>((float4*)acc, (const float4*)B, (float4*)A);
        lgcn_scatter<<<SC_BLOCKS, 256, 0, stream>>>(B, A, row, col, ew);
        lgcn_addzero<<<2048, 256, 0, stream>>>((float4*)acc, (const float4*)A, (float4*)B);
        lgcn_scatter<<<SC_BLOCKS, 256, 0, stream>>>(A, B, row, col, ew);
        lgcn_final<<<2048, 256, 0, stream>>>((float4*)acc, (const float4*)B);
    }
}

// Round 14
// 396.218 us; speedup vs baseline: 2.6385x; 1.1279x over previous
//
#include <hip/hip_runtime.h>

// LightGCN via CSR build + 8-nodes/wave bf16 gather layers, unconditional
// clamped batch loads (forces 8-deep MLP without fences).
// E16 = bf16(emb); X1 = G(E16); X2 = G(X1); out = 0.25*(emb+X1+X2+G(X2))
// G(x)[c] = sum_{e: col[e]=c} w[e] * x[row[e]].  fp32 accumulation.

#define NNODES   500000
#define DIMV     64
#define NEDGE    1250000
#define NELEM    (NNODES * DIMV)          // 32,000,000
#define NELEM4   (NELEM / 4)

#define SCAN_BLK   256
#define SCAN_ITEMS 8
#define SCAN_CHUNK (SCAN_BLK * SCAN_ITEMS)              // 2048
#define NB1 ((NNODES + SCAN_CHUNK - 1) / SCAN_CHUNK)    // 245 (<= 256)

// bf16 helpers (RNE)
static __device__ __forceinline__ unsigned short f2bf(float f) {
    unsigned u = __float_as_uint(f);
    unsigned r = (u + 0x7fffu + ((u >> 16) & 1u)) >> 16;
    return (unsigned short)r;
}
static __device__ __forceinline__ float bflo(unsigned u) {
    return __uint_as_float(u << 16);
}
static __device__ __forceinline__ float bfhi(unsigned u) {
    return __uint_as_float(u & 0xffff0000u);
}

// ======================= emb -> bf16 table =======================
__global__ __launch_bounds__(256) void lgcn_cvt(
    const float4* __restrict__ emb4, unsigned long long* __restrict__ dst)
{
    int i = blockIdx.x * blockDim.x + threadIdx.x;
    int stride = gridDim.x * blockDim.x;
    for (; i < NELEM4; i += stride) {
        float4 v = emb4[i];
        unsigned lo = (unsigned)f2bf(v.x) | ((unsigned)f2bf(v.y) << 16);
        unsigned hi = (unsigned)f2bf(v.z) | ((unsigned)f2bf(v.w) << 16);
        unsigned long long o = (unsigned long long)lo | ((unsigned long long)hi << 32);
        __builtin_nontemporal_store(o, &dst[i]);
    }
}

// ======================= CSR build =======================

__global__ __launch_bounds__(256) void lgcn_hist(
    const int* __restrict__ col, int* __restrict__ cnt)
{
    int e = blockIdx.x * blockDim.x + threadIdx.x;
    if (e >= NEDGE) return;
    int c = col[e];
    if ((unsigned)c >= NNODES) return;       // insurance; never triggers
    atomicAdd(&cnt[c], 1);
}

__global__ __launch_bounds__(SCAN_BLK) void lgcn_scan1(
    const int* __restrict__ cnt, int* __restrict__ startv, int* __restrict__ bsum)
{
    __shared__ int sh[SCAN_BLK];
    int b = blockIdx.x;
    int base = b * SCAN_CHUNK;
    int tid = threadIdx.x;
    int v[SCAN_ITEMS];
    int local = 0;
    #pragma unroll
    for (int k = 0; k < SCAN_ITEMS; ++k) {
        int idx = base + tid * SCAN_ITEMS + k;
        v[k] = (idx < NNODES) ? cnt[idx] : 0;
        local += v[k];
    }
    sh[tid] = local;
    __syncthreads();
    for (int off = 1; off < SCAN_BLK; off <<= 1) {
        int x = (tid >= off) ? sh[tid - off] : 0;
        __syncthreads();
        sh[tid] += x;
        __syncthreads();
    }
    int run = (tid == 0) ? 0 : sh[tid - 1];
    if (tid == SCAN_BLK - 1) bsum[b] = sh[tid];
    #pragma unroll
    for (int k = 0; k < SCAN_ITEMS; ++k) {
        int idx = base + tid * SCAN_ITEMS + k;
        if (idx < NNODES) startv[idx] = run;
        run += v[k];
    }
}

__global__ __launch_bounds__(SCAN_BLK) void lgcn_scan2(int* __restrict__ bsum)
{
    __shared__ int sh[SCAN_BLK];
    int tid = threadIdx.x;
    sh[tid] = (tid < NB1) ? bsum[tid] : 0;
    __syncthreads();
    for (int off = 1; off < SCAN_BLK; off <<= 1) {
        int x = (tid >= off) ? sh[tid - off] : 0;
        __syncthreads();
        sh[tid] += x;
        __syncthreads();
    }
    if (tid < NB1) bsum[tid] = (tid == 0) ? 0 : sh[tid - 1];
}

__global__ __launch_bounds__(256) void lgcn_scan3(
    int* __restrict__ startv, int* __restrict__ cursor, const int* __restrict__ bsum)
{
    int i = blockIdx.x * blockDim.x + threadIdx.x;
    if (i < NNODES) {
        int s = startv[i] + bsum[i / SCAN_CHUNK];
        startv[i] = s;
        cursor[i] = s;
    }
    if (i == 0) startv[NNODES] = NEDGE;
}

__global__ __launch_bounds__(256) void lgcn_fill(
    const int* __restrict__ row, const int* __restrict__ col,
    const float* __restrict__ w, int* __restrict__ cursor, int2* __restrict__ pairs)
{
    int e = blockIdx.x * blockDim.x + threadIdx.x;
    if (e >= NEDGE) return;
    int c = col[e];
    if ((unsigned)c >= NNODES) return;       // must match lgcn_hist's guard
    int r = row[e];
    float wt = w[e];
    if ((unsigned)r >= NNODES) { r = 0; wt = 0.f; }   // insurance
    int p = atomicAdd(&cursor[c], 1);
    pairs[p] = make_int2(r, __float_as_int(wt));
}

// ======================= gather: 8 nodes/wave, 8 lanes/node =======================
// Lane sub = 8 consecutive dims (uint4 = 8 bf16 = 16 B). Per row-load
// instruction: 8 groups x 128 B = 1 KB random in flight; U=8 batches.
// Loads are UNCONDITIONAL with clamped index (idx<=e-1); padding edges get
// w=0 via select -> no control flow inside batch -> compiler keeps 8 deep.
// MODE 0: E16 -> X1 bf16;  MODE 1: X1 -> X2 bf16
// MODE 2: X2 + streams -> out fp32 = 0.25*(emb+X1+X2+G)
template<int MODE>
__global__ __launch_bounds__(256, 4) void lgcn_gather(
    const unsigned short* __restrict__ src16, unsigned short* __restrict__ xout16,
    const float* __restrict__ emb, const unsigned short* __restrict__ x1,
    const unsigned short* __restrict__ x2, float* __restrict__ outp,
    const int2* __restrict__ pairs, const int* __restrict__ startv)
{
    int t = blockIdx.x * blockDim.x + threadIdx.x;
    int wid = t >> 6;               // wave id: 8 nodes/wave
    int lane = t & 63;
    int g = lane >> 3;              // node slot (0..7)
    int sub = lane & 7;             // dim octet (dims sub*8 .. sub*8+7)
    int n = wid * 8 + g;
    if (n >= NNODES) return;

    int s = startv[n];              // broadcast within 8-lane group
    int e = startv[n + 1];

    float a0=0.f,a1=0.f,a2=0.f,a3=0.f,a4=0.f,a5=0.f,a6=0.f,a7=0.f;

    for (int i = s; i < e; i += 8) {     // empty nodes skip entirely (exec mask)
        int2 pr[8];
        #pragma unroll
        for (int k = 0; k < 8; ++k) {
            int idx = i + k;
            idx = idx < e ? idx : e - 1;     // clamp; e>s here so e-1>=s
            pr[k] = pairs[idx];              // unconditional broadcast load
        }
        uint4 rv[8];
        #pragma unroll
        for (int k = 0; k < 8; ++k) {
            rv[k] = *reinterpret_cast<const uint4*>(
                &src16[(size_t)pr[k].x * DIMV + sub * 8]);   // unconditional
        }
        #pragma unroll
        for (int k = 0; k < 8; ++k) {
            float wk = (i + k < e) ? __int_as_float(pr[k].y) : 0.f;
            a0 = fmaf(wk, bflo(rv[k].x), a0);
            a1 = fmaf(wk, bfhi(rv[k].x), a1);
            a2 = fmaf(wk, bflo(rv[k].y), a2);
            a3 = fmaf(wk, bfhi(rv[k].y), a3);
            a4 = fmaf(wk, bflo(rv[k].z), a4);
            a5 = fmaf(wk, bfhi(rv[k].z), a5);
            a6 = fmaf(wk, bflo(rv[k].w), a6);
            a7 = fmaf(wk, bfhi(rv[k].w), a7);
        }
    }

    const size_t o = (size_t)n * DIMV + sub * 8;
    if (MODE == 2) {
        float4 e0 = *reinterpret_cast<const float4*>(&emb[o]);
        float4 e1 = *reinterpret_cast<const float4*>(&emb[o + 4]);
        uint4 u1 = *reinterpret_cast<const uint4*>(&x1[o]);
        uint4 u2 = *reinterpret_cast<const uint4*>(&x2[o]);
        float4 r0, r1;
        r0.x = (e0.x + bflo(u1.x) + bflo(u2.x) + a0) * 0.25f;
        r0.y = (e0.y + bfhi(u1.x) + bfhi(u2.x) + a1) * 0.25f;
        r0.z = (e0.z + bflo(u1.y) + bflo(u2.y) + a2) * 0.25f;
        r0.w = (e0.w + bfhi(u1.y) + bfhi(u2.y) + a3) * 0.25f;
        r1.x = (e1.x + bflo(u1.z) + bflo(u2.z) + a4) * 0.25f;
        r1.y = (e1.y + bfhi(u1.z) + bfhi(u2.z) + a5) * 0.25f;
        r1.z = (e1.z + bflo(u1.w) + bflo(u2.w) + a6) * 0.25f;
        r1.w = (e1.w + bfhi(u1.w) + bfhi(u2.w) + a7) * 0.25f;
        *reinterpret_cast<float4*>(&outp[o])     = r0;
        *reinterpret_cast<float4*>(&outp[o + 4]) = r1;
    } else {
        unsigned long long lo =
              (unsigned long long)((unsigned)f2bf(a0) | ((unsigned)f2bf(a1) << 16))
            | ((unsigned long long)((unsigned)f2bf(a2) | ((unsigned)f2bf(a3) << 16)) << 32);
        unsigned long long hi =
              (unsigned long long)((unsigned)f2bf(a4) | ((unsigned)f2bf(a5) << 16))
            | ((unsigned long long)((unsigned)f2bf(a6) | ((unsigned)f2bf(a7) << 16)) << 32);
        __builtin_nontemporal_store(lo, reinterpret_cast<unsigned long long*>(&xout16[o]));
        __builtin_nontemporal_store(hi, reinterpret_cast<unsigned long long*>(&xout16[o + 4]));
    }
}

// ======================= fallback: atomic scatter path (fp32) =======================

__global__ __launch_bounds__(256) void lgcn_init(
    const float4* __restrict__ emb, float4* __restrict__ acc,
    float4* __restrict__ A, float4* __restrict__ B)
{
    int i = blockIdx.x * blockDim.x + threadIdx.x;
    int stride = gridDim.x * blockDim.x;
    for (; i < NELEM4; i += stride) {
        float4 v = emb[i];
        acc[i] = v;
        A[i]   = v;
        B[i]   = make_float4(0.f, 0.f, 0.f, 0.f);
    }
}

__global__ __launch_bounds__(256) void lgcn_scatter(
    const float* __restrict__ xcur, float* __restrict__ xnext,
    const int* __restrict__ row, const int* __restrict__ col,
    const float* __restrict__ w)
{
    int t = blockIdx.x * blockDim.x + threadIdx.x;
    int e = t >> 4;
    if (e >= NEDGE) return;
    int d = (t & 15) << 2;
    int r = row[e];
    int c = col[e];
    if ((unsigned)r >= NNODES || (unsigned)c >= NNODES) return;
    float wt = w[e];
    const float4 v = *reinterpret_cast<const float4*>(xcur + (size_t)r * DIMV + d);
    float* dst = xnext + (size_t)c * DIMV + d;
    atomicAdd(dst + 0, wt * v.x);
    atomicAdd(dst + 1, wt * v.y);
    atomicAdd(dst + 2, wt * v.z);
    atomicAdd(dst + 3, wt * v.w);
}

__global__ __launch_bounds__(256) void lgcn_addzero(
    float4* __restrict__ acc, const float4* __restrict__ X, float4* __restrict__ Y)
{
    int i = blockIdx.x * blockDim.x + threadIdx.x;
    int stride = gridDim.x * blockDim.x;
    for (; i < NELEM4; i += stride) {
        float4 a = acc[i];
        float4 x = X[i];
        a.x += x.x; a.y += x.y; a.z += x.z; a.w += x.w;
        acc[i] = a;
        Y[i] = make_float4(0.f, 0.f, 0.f, 0.f);
    }
}

__global__ __launch_bounds__(256) void lgcn_final(
    float4* __restrict__ acc, const float4* __restrict__ X)
{
    int i = blockIdx.x * blockDim.x + threadIdx.x;
    int stride = gridDim.x * blockDim.x;
    for (; i < NELEM4; i += stride) {
        float4 a = acc[i];
        float4 x = X[i];
        a.x = (a.x + x.x) * 0.25f;
        a.y = (a.y + x.y) * 0.25f;
        a.z = (a.z + x.z) * 0.25f;
        a.w = (a.w + x.w) * 0.25f;
        acc[i] = a;
    }
}

// ======================= launch =======================

extern "C" void kernel_launch(void* const* d_in, const int* in_sizes, int n_in,
                              void* d_out, int out_size, void* d_ws, size_t ws_size,
                              hipStream_t stream) {
    const float* emb  = (const float*)d_in[0];   // [N, 64] fp32
    const int*   eidx = (const int*)d_in[1];     // [2, E] int32
    const float* ew   = (const float*)d_in[2];   // [E] fp32
    float* acc = (float*)d_out;                  // [N, 64]

    const int* row = eidx;
    const int* col = eidx + NEDGE;

    // workspace: E16, X1, X2 (bf16, 64 MB each) + CSR arrays
    unsigned short* E16 = (unsigned short*)d_ws;         // NELEM*2
    unsigned short* X1  = E16 + NELEM;                   // NELEM*2
    unsigned short* X2  = X1 + NELEM;                    // NELEM*2
    int2*  pairs  = (int2*)(X2 + NELEM);                 // 10e6 B (8-aligned)
    int*   startv = (int*)(pairs + NEDGE);               // (N+1)*4
    int*   cursor = startv + (NNODES + 1);               // N*4
    int*   bsum   = cursor + NNODES;                     // NB1*4
    const size_t needed = (size_t)3 * NELEM * 2 + (size_t)NEDGE * 8
                        + ((size_t)NNODES + 1) * 4 + (size_t)NNODES * 4 + (size_t)NB1 * 4;

    const int EDGE_BLOCKS = (NEDGE + 255) / 256;
    const int NODE_BLOCKS = (NNODES + 255) / 256;
    const int GW_BLOCKS   = (NNODES * 8 + 255) / 256;    // 8 nodes/wave -> 62500 waves

    if (ws_size >= needed) {
        // ---- emb -> bf16 table ----
        lgcn_cvt<<<2048, 256, 0, stream>>>((const float4*)emb, (unsigned long long*)E16);

        // ---- CSR build ----
        hipMemsetAsync(cursor, 0, (size_t)NNODES * 4, stream);
        lgcn_hist<<<EDGE_BLOCKS, 256, 0, stream>>>(col, cursor);
        lgcn_scan1<<<NB1, SCAN_BLK, 0, stream>>>(cursor, startv, bsum);
        lgcn_scan2<<<1, SCAN_BLK, 0, stream>>>(bsum);
        lgcn_scan3<<<NODE_BLOCKS, 256, 0, stream>>>(startv, cursor, bsum);
        lgcn_fill<<<EDGE_BLOCKS, 256, 0, stream>>>(row, col, ew, cursor, pairs);

        // ---- layers ----
        lgcn_gather<0><<<GW_BLOCKS, 256, 0, stream>>>(
            E16, X1, nullptr, nullptr, nullptr, nullptr, pairs, startv);
        lgcn_gather<1><<<GW_BLOCKS, 256, 0, stream>>>(
            X1, X2, nullptr, nullptr, nullptr, nullptr, pairs, startv);
        lgcn_gather<2><<<GW_BLOCKS, 256, 0, stream>>>(
            X2, nullptr, emb, X1, X2, acc, pairs, startv);
    } else {
        // ---- fallback: proven fp32 atomic-scatter path ----
        float* A = (float*)d_ws;
        float* B = A + NELEM;
        const int SC_BLOCKS = (NEDGE * 16 + 255) / 256;
        lgcn_init<<<2048, 256, 0, stream>>>(
            (const float4*)emb, (float4*)acc, (float4*)A, (float4*)B);
        lgcn_scatter<<<SC_BLOCKS, 256, 0, stream>>>(A, B, row, col, ew);
        lgcn_addzero<<<2048, 256, 0, stream>>>((float4*)acc, (const float4*)B, (float4*)A);
        lgcn_scatter<<<SC_BLOCKS, 256, 0, stream>>>(B, A, row, col, ew);
        lgcn_addzero<<<2048, 256, 0, stream>>>((float4*)acc, (const float4*)A, (float4*)B);
        lgcn_scatter<<<SC_BLOCKS, 256, 0, stream>>>(A, B, row, col, ew);
        lgcn_final<<<2048, 256, 0, stream>>>((float4*)acc, (const float4*)B);
    }
}

// Round 15
// 381.570 us; speedup vs baseline: 2.7398x; 1.0384x over previous
//
#include <hip/hip_runtime.h>

// LightGCN: fused cvt+hist, CSR fill (nt stores), 8-nodes/wave bf16 gathers.
// E16 = bf16(emb); X1 = G(E16); X2 = G(X1); out = 0.25*(emb+X1+X2+G(X2))
// G(x)[c] = sum_{e: col[e]=c} w[e] * x[row[e]].  fp32 accumulation.

#define NNODES   500000
#define DIMV     64
#define NEDGE    1250000
#define NELEM    (NNODES * DIMV)          // 32,000,000
#define NELEM4   (NELEM / 4)

#define SCAN_BLK   256
#define SCAN_ITEMS 8
#define SCAN_CHUNK (SCAN_BLK * SCAN_ITEMS)              // 2048
#define NB1 ((NNODES + SCAN_CHUNK - 1) / SCAN_CHUNK)    // 245 (<= 256)

#define CVT_BLOCKS  1024
#define EDGE2_BLOCKS ((NEDGE / 2 + 255) / 256)          // 2442

typedef float  fx4 __attribute__((ext_vector_type(4)));
typedef unsigned ux4 __attribute__((ext_vector_type(4)));

// bf16 helpers (RNE)
static __device__ __forceinline__ unsigned short f2bf(float f) {
    unsigned u = __float_as_uint(f);
    unsigned r = (u + 0x7fffu + ((u >> 16) & 1u)) >> 16;
    return (unsigned short)r;
}
static __device__ __forceinline__ float bflo(unsigned u) {
    return __uint_as_float(u << 16);
}
static __device__ __forceinline__ float bfhi(unsigned u) {
    return __uint_as_float(u & 0xffff0000u);
}

// ============ fused: emb->bf16 cvt (blocks [0,CVT)) + hist (rest) ============
__global__ __launch_bounds__(256) void lgcn_cvt_hist(
    const float4* __restrict__ emb4, unsigned long long* __restrict__ dst,
    const int* __restrict__ col, int* __restrict__ cnt)
{
    if (blockIdx.x < CVT_BLOCKS) {
        int i = blockIdx.x * 256 + threadIdx.x;
        const int stride = CVT_BLOCKS * 256;
        for (; i < NELEM4; i += stride) {
            float4 v = emb4[i];
            unsigned lo = (unsigned)f2bf(v.x) | ((unsigned)f2bf(v.y) << 16);
            unsigned hi = (unsigned)f2bf(v.z) | ((unsigned)f2bf(v.w) << 16);
            unsigned long long o = (unsigned long long)lo | ((unsigned long long)hi << 32);
            __builtin_nontemporal_store(o, &dst[i]);
        }
    } else {
        int t = (blockIdx.x - CVT_BLOCKS) * 256 + threadIdx.x;
        if (t >= NEDGE / 2) return;
        int2 c2 = reinterpret_cast<const int2*>(col)[t];
        if ((unsigned)c2.x < NNODES) atomicAdd(&cnt[c2.x], 1);
        if ((unsigned)c2.y < NNODES) atomicAdd(&cnt[c2.y], 1);
    }
}

// ======================= CSR scans =======================

__global__ __launch_bounds__(SCAN_BLK) void lgcn_scan1(
    const int* __restrict__ cnt, int* __restrict__ startv, int* __restrict__ bsum)
{
    __shared__ int sh[SCAN_BLK];
    int b = blockIdx.x;
    int base = b * SCAN_CHUNK;
    int tid = threadIdx.x;
    int v[SCAN_ITEMS];
    int local = 0;
    #pragma unroll
    for (int k = 0; k < SCAN_ITEMS; ++k) {
        int idx = base + tid * SCAN_ITEMS + k;
        v[k] = (idx < NNODES) ? cnt[idx] : 0;
        local += v[k];
    }
    sh[tid] = local;
    __syncthreads();
    for (int off = 1; off < SCAN_BLK; off <<= 1) {
        int x = (tid >= off) ? sh[tid - off] : 0;
        __syncthreads();
        sh[tid] += x;
        __syncthreads();
    }
    int run = (tid == 0) ? 0 : sh[tid - 1];
    if (tid == SCAN_BLK - 1) bsum[b] = sh[tid];
    #pragma unroll
    for (int k = 0; k < SCAN_ITEMS; ++k) {
        int idx = base + tid * SCAN_ITEMS + k;
        if (idx < NNODES) startv[idx] = run;
        run += v[k];
    }
}

__global__ __launch_bounds__(SCAN_BLK) void lgcn_scan2(int* __restrict__ bsum)
{
    __shared__ int sh[SCAN_BLK];
    int tid = threadIdx.x;
    sh[tid] = (tid < NB1) ? bsum[tid] : 0;
    __syncthreads();
    for (int off = 1; off < SCAN_BLK; off <<= 1) {
        int x = (tid >= off) ? sh[tid - off] : 0;
        __syncthreads();
        sh[tid] += x;
        __syncthreads();
    }
    if (tid < NB1) bsum[tid] = (tid == 0) ? 0 : sh[tid - 1];
}

__global__ __launch_bounds__(256) void lgcn_scan3(
    int* __restrict__ startv, int* __restrict__ cursor, const int* __restrict__ bsum)
{
    int i = blockIdx.x * blockDim.x + threadIdx.x;
    if (i < NNODES) {
        int s = startv[i] + bsum[i / SCAN_CHUNK];
        startv[i] = s;
        cursor[i] = s;
    }
    if (i == 0) startv[NNODES] = NEDGE;
}

// ============ fill: 2 edges/thread, nontemporal pair stores ============
__global__ __launch_bounds__(256) void lgcn_fill(
    const int* __restrict__ row, const int* __restrict__ col,
    const float* __restrict__ w, int* __restrict__ cursor,
    unsigned long long* __restrict__ pairs)
{
    int t = blockIdx.x * blockDim.x + threadIdx.x;
    if (t >= NEDGE / 2) return;
    int2   c2 = reinterpret_cast<const int2*>(col)[t];
    int2   r2 = reinterpret_cast<const int2*>(row)[t];
    float2 w2 = reinterpret_cast<const float2*>(w)[t];

    if ((unsigned)c2.x < NNODES) {          // must match hist's guard
        int r = r2.x; float wt = w2.x;
        if ((unsigned)r >= NNODES) { r = 0; wt = 0.f; }
        int p = atomicAdd(&cursor[c2.x], 1);
        unsigned long long pk = (unsigned long long)(unsigned)r
                              | ((unsigned long long)__float_as_uint(wt) << 32);
        __builtin_nontemporal_store(pk, &pairs[p]);
    }
    if ((unsigned)c2.y < NNODES) {
        int r = r2.y; float wt = w2.y;
        if ((unsigned)r >= NNODES) { r = 0; wt = 0.f; }
        int p = atomicAdd(&cursor[c2.y], 1);
        unsigned long long pk = (unsigned long long)(unsigned)r
                              | ((unsigned long long)__float_as_uint(wt) << 32);
        __builtin_nontemporal_store(pk, &pairs[p]);
    }
}

// ======================= gather: 8 nodes/wave, 8 lanes/node =======================
// Lane sub = 8 consecutive dims (uint4 = 8 bf16 = 16 B). Unconditional clamped
// batch loads keep 8 rows in flight per group (r14-proven structure).
// MODE 0: E16 -> X1 bf16;  MODE 1: X1 -> X2 bf16
// MODE 2: X2 + streams -> out fp32 = 0.25*(emb+X1+X2+G)  (nt streams)
template<int MODE>
__global__ __launch_bounds__(256, 4) void lgcn_gather(
    const unsigned short* __restrict__ src16, unsigned short* __restrict__ xout16,
    const float* __restrict__ emb, const unsigned short* __restrict__ x1,
    const unsigned short* __restrict__ x2, float* __restrict__ outp,
    const int2* __restrict__ pairs, const int* __restrict__ startv)
{
    int t = blockIdx.x * blockDim.x + threadIdx.x;
    int wid = t >> 6;               // wave id: 8 nodes/wave
    int lane = t & 63;
    int g = lane >> 3;              // node slot (0..7)
    int sub = lane & 7;             // dim octet (dims sub*8 .. sub*8+7)
    int n = wid * 8 + g;
    if (n >= NNODES) return;

    int s = startv[n];              // broadcast within 8-lane group
    int e = startv[n + 1];

    float a0=0.f,a1=0.f,a2=0.f,a3=0.f,a4=0.f,a5=0.f,a6=0.f,a7=0.f;

    for (int i = s; i < e; i += 8) {     // empty nodes skip entirely
        int2 pr[8];
        #pragma unroll
        for (int k = 0; k < 8; ++k) {
            int idx = i + k;
            idx = idx < e ? idx : e - 1;     // clamp; e>s here so e-1>=s
            pr[k] = pairs[idx];              // unconditional broadcast load
        }
        uint4 rv[8];
        #pragma unroll
        for (int k = 0; k < 8; ++k) {
            rv[k] = *reinterpret_cast<const uint4*>(
                &src16[(size_t)pr[k].x * DIMV + sub * 8]);   // unconditional
        }
        #pragma unroll
        for (int k = 0; k < 8; ++k) {
            float wk = (i + k < e) ? __int_as_float(pr[k].y) : 0.f;
            a0 = fmaf(wk, bflo(rv[k].x), a0);
            a1 = fmaf(wk, bfhi(rv[k].x), a1);
            a2 = fmaf(wk, bflo(rv[k].y), a2);
            a3 = fmaf(wk, bfhi(rv[k].y), a3);
            a4 = fmaf(wk, bflo(rv[k].z), a4);
            a5 = fmaf(wk, bfhi(rv[k].z), a5);
            a6 = fmaf(wk, bflo(rv[k].w), a6);
            a7 = fmaf(wk, bfhi(rv[k].w), a7);
        }
    }

    const size_t o = (size_t)n * DIMV + sub * 8;
    if (MODE == 2) {
        fx4 e0 = __builtin_nontemporal_load(reinterpret_cast<const fx4*>(&emb[o]));
        fx4 e1 = __builtin_nontemporal_load(reinterpret_cast<const fx4*>(&emb[o + 4]));
        ux4 u1 = __builtin_nontemporal_load(reinterpret_cast<const ux4*>(&x1[o]));
        uint4 u2 = *reinterpret_cast<const uint4*>(&x2[o]);
        fx4 r0, r1;
        r0.x = (e0.x + bflo(u1.x) + bflo(u2.x) + a0) * 0.25f;
        r0.y = (e0.y + bfhi(u1.x) + bfhi(u2.x) + a1) * 0.25f;
        r0.z = (e0.z + bflo(u1.y) + bflo(u2.y) + a2) * 0.25f;
        r0.w = (e0.w + bfhi(u1.y) + bfhi(u2.y) + a3) * 0.25f;
        r1.x = (e1.x + bflo(u1.z) + bflo(u2.z) + a4) * 0.25f;
        r1.y = (e1.y + bfhi(u1.z) + bfhi(u2.z) + a5) * 0.25f;
        r1.z = (e1.z + bflo(u1.w) + bflo(u2.w) + a6) * 0.25f;
        r1.w = (e1.w + bfhi(u1.w) + bfhi(u2.w) + a7) * 0.25f;
        __builtin_nontemporal_store(r0, reinterpret_cast<fx4*>(&outp[o]));
        __builtin_nontemporal_store(r1, reinterpret_cast<fx4*>(&outp[o + 4]));
    } else {
        unsigned long long lo =
              (unsigned long long)((unsigned)f2bf(a0) | ((unsigned)f2bf(a1) << 16))
            | ((unsigned long long)((unsigned)f2bf(a2) | ((unsigned)f2bf(a3) << 16)) << 32);
        unsigned long long hi =
              (unsigned long long)((unsigned)f2bf(a4) | ((unsigned)f2bf(a5) << 16))
            | ((unsigned long long)((unsigned)f2bf(a6) | ((unsigned)f2bf(a7) << 16)) << 32);
        __builtin_nontemporal_store(lo, reinterpret_cast<unsigned long long*>(&xout16[o]));
        __builtin_nontemporal_store(hi, reinterpret_cast<unsigned long long*>(&xout16[o + 4]));
    }
}

// ======================= fallback: atomic scatter path (fp32) =======================

__global__ __launch_bounds__(256) void lgcn_init(
    const float4* __restrict__ emb, float4* __restrict__ acc,
    float4* __restrict__ A, float4* __restrict__ B)
{
    int i = blockIdx.x * blockDim.x + threadIdx.x;
    int stride = gridDim.x * blockDim.x;
    for (; i < NELEM4; i += stride) {
        float4 v = emb[i];
        acc[i] = v;
        A[i]   = v;
        B[i]   = make_float4(0.f, 0.f, 0.f, 0.f);
    }
}

__global__ __launch_bounds__(256) void lgcn_scatter(
    const float* __restrict__ xcur, float* __restrict__ xnext,
    const int* __restrict__ row, const int* __restrict__ col,
    const float* __restrict__ w)
{
    int t = blockIdx.x * blockDim.x + threadIdx.x;
    int e = t >> 4;
    if (e >= NEDGE) return;
    int d = (t & 15) << 2;
    int r = row[e];
    int c = col[e];
    if ((unsigned)r >= NNODES || (unsigned)c >= NNODES) return;
    float wt = w[e];
    const float4 v = *reinterpret_cast<const float4*>(xcur + (size_t)r * DIMV + d);
    float* dst = xnext + (size_t)c * DIMV + d;
    atomicAdd(dst + 0, wt * v.x);
    atomicAdd(dst + 1, wt * v.y);
    atomicAdd(dst + 2, wt * v.z);
    atomicAdd(dst + 3, wt * v.w);
}

__global__ __launch_bounds__(256) void lgcn_addzero(
    float4* __restrict__ acc, const float4* __restrict__ X, float4* __restrict__ Y)
{
    int i = blockIdx.x * blockDim.x + threadIdx.x;
    int stride = gridDim.x * blockDim.x;
    for (; i < NELEM4; i += stride) {
        float4 a = acc[i];
        float4 x = X[i];
        a.x += x.x; a.y += x.y; a.z += x.z; a.w += x.w;
        acc[i] = a;
        Y[i] = make_float4(0.f, 0.f, 0.f, 0.f);
    }
}

__global__ __launch_bounds__(256) void lgcn_final(
    float4* __restrict__ acc, const float4* __restrict__ X)
{
    int i = blockIdx.x * blockDim.x + threadIdx.x;
    int stride = gridDim.x * blockDim.x;
    for (; i < NELEM4; i += stride) {
        float4 a = acc[i];
        float4 x = X[i];
        a.x = (a.x + x.x) * 0.25f;
        a.y = (a.y + x.y) * 0.25f;
        a.z = (a.z + x.z) * 0.25f;
        a.w = (a.w + x.w) * 0.25f;
        acc[i] = a;
    }
}

// ======================= launch =======================

extern "C" void kernel_launch(void* const* d_in, const int* in_sizes, int n_in,
                              void* d_out, int out_size, void* d_ws, size_t ws_size,
                              hipStream_t stream) {
    const float* emb  = (const float*)d_in[0];   // [N, 64] fp32
    const int*   eidx = (const int*)d_in[1];     // [2, E] int32
    const float* ew   = (const float*)d_in[2];   // [E] fp32
    float* acc = (float*)d_out;                  // [N, 64]

    const int* row = eidx;
    const int* col = eidx + NEDGE;

    // workspace: E16, X1, X2 (bf16, 64 MB each) + CSR arrays
    unsigned short* E16 = (unsigned short*)d_ws;         // NELEM*2
    unsigned short* X1  = E16 + NELEM;                   // NELEM*2
    unsigned short* X2  = X1 + NELEM;                    // NELEM*2
    int2*  pairs  = (int2*)(X2 + NELEM);                 // 10e6 B (8-aligned)
    int*   startv = (int*)(pairs + NEDGE);               // (N+1)*4
    int*   cursor = startv + (NNODES + 1);               // N*4
    int*   bsum   = cursor + NNODES;                     // NB1*4
    const size_t needed = (size_t)3 * NELEM * 2 + (size_t)NEDGE * 8
                        + ((size_t)NNODES + 1) * 4 + (size_t)NNODES * 4 + (size_t)NB1 * 4;

    const int NODE_BLOCKS = (NNODES + 255) / 256;
    const int GW_BLOCKS   = (NNODES * 8 + 255) / 256;    // 8 nodes/wave

    if (ws_size >= needed) {
        // ---- CSR counts + bf16 table (fused) ----
        hipMemsetAsync(cursor, 0, (size_t)NNODES * 4, stream);
        lgcn_cvt_hist<<<CVT_BLOCKS + EDGE2_BLOCKS, 256, 0, stream>>>(
            (const float4*)emb, (unsigned long long*)E16, col, cursor);

        // ---- scans + fill ----
        lgcn_scan1<<<NB1, SCAN_BLK, 0, stream>>>(cursor, startv, bsum);
        lgcn_scan2<<<1, SCAN_BLK, 0, stream>>>(bsum);
        lgcn_scan3<<<NODE_BLOCKS, 256, 0, stream>>>(startv, cursor, bsum);
        lgcn_fill<<<EDGE2_BLOCKS, 256, 0, stream>>>(
            row, col, ew, cursor, (unsigned long long*)pairs);

        // ---- layers ----
        lgcn_gather<0><<<GW_BLOCKS, 256, 0, stream>>>(
            E16, X1, nullptr, nullptr, nullptr, nullptr, pairs, startv);
        lgcn_gather<1><<<GW_BLOCKS, 256, 0, stream>>>(
            X1, X2, nullptr, nullptr, nullptr, nullptr, pairs, startv);
        lgcn_gather<2><<<GW_BLOCKS, 256, 0, stream>>>(
            X2, nullptr, emb, X1, X2, acc, pairs, startv);
    } else {
        // ---- fallback: proven fp32 atomic-scatter path ----
        float* A = (float*)d_ws;
        float* B = A + NELEM;
        const int SC_BLOCKS = (NEDGE * 16 + 255) / 256;
        lgcn_init<<<2048, 256, 0, stream>>>(
            (const float4*)emb, (float4*)acc, (float4*)A, (float4*)B);
        lgcn_scatter<<<SC_BLOCKS, 256, 0, stream>>>(A, B, row, col, ew);
        lgcn_addzero<<<2048, 256, 0, stream>>>((float4*)acc, (const float4*)B, (float4*)A);
        lgcn_scatter<<<SC_BLOCKS, 256, 0, stream>>>(B, A, row, col, ew);
        lgcn_addzero<<<2048, 256, 0, stream>>>((float4*)acc, (const float4*)A, (float4*)B);
        lgcn_scatter<<<SC_BLOCKS, 256, 0, stream>>>(A, B, row, col, ew);
        lgcn_final<<<2048, 256, 0, stream>>>((float4*)acc, (const float4*)B);
    }
}

// Round 16
// 349.009 us; speedup vs baseline: 2.9954x; 1.0933x over previous
//
#include <hip/hip_runtime.h>

// LightGCN: fused cvt+hist, XCD-class-partitioned CSR fill, 8-nodes/wave
// bf16 gathers. E16 = bf16(emb); X1 = G(E16); X2 = G(X1);
// out = 0.25*(emb+X1+X2+G(X2)).  fp32 accumulation.

#define NNODES   500000
#define DIMV     64
#define NEDGE    1250000
#define NELEM    (NNODES * DIMV)          // 32,000,000
#define NELEM4   (NELEM / 4)

#define SCAN_BLK   256
#define SCAN_ITEMS 8
#define SCAN_CHUNK (SCAN_BLK * SCAN_ITEMS)              // 2048
#define NB1 ((NNODES + SCAN_CHUNK - 1) / SCAN_CHUNK)    // 245 (<= 256)

#define CVT_BLOCKS  1024
#define EDGE2_BLOCKS ((NEDGE / 2 + 255) / 256)          // 2442

#define FILL_CLASSES  8
#define FILL_BPC      256                                // blocks per class
#define COLS_PER_CLS  (NNODES / FILL_CLASSES)            // 62500

typedef float  fx4 __attribute__((ext_vector_type(4)));
typedef unsigned ux4 __attribute__((ext_vector_type(4)));

// bf16 helpers (RNE)
static __device__ __forceinline__ unsigned short f2bf(float f) {
    unsigned u = __float_as_uint(f);
    unsigned r = (u + 0x7fffu + ((u >> 16) & 1u)) >> 16;
    return (unsigned short)r;
}
static __device__ __forceinline__ float bflo(unsigned u) {
    return __uint_as_float(u << 16);
}
static __device__ __forceinline__ float bfhi(unsigned u) {
    return __uint_as_float(u & 0xffff0000u);
}

// ============ fused: emb->bf16 cvt (blocks [0,CVT)) + hist (rest) ============
__global__ __launch_bounds__(256) void lgcn_cvt_hist(
    const float4* __restrict__ emb4, unsigned long long* __restrict__ dst,
    const int* __restrict__ col, int* __restrict__ cnt)
{
    if (blockIdx.x < CVT_BLOCKS) {
        int i = blockIdx.x * 256 + threadIdx.x;
        const int stride = CVT_BLOCKS * 256;
        for (; i < NELEM4; i += stride) {
            float4 v = emb4[i];
            unsigned lo = (unsigned)f2bf(v.x) | ((unsigned)f2bf(v.y) << 16);
            unsigned hi = (unsigned)f2bf(v.z) | ((unsigned)f2bf(v.w) << 16);
            unsigned long long o = (unsigned long long)lo | ((unsigned long long)hi << 32);
            __builtin_nontemporal_store(o, &dst[i]);
        }
    } else {
        int t = (blockIdx.x - CVT_BLOCKS) * 256 + threadIdx.x;
        if (t >= NEDGE / 2) return;
        int2 c2 = reinterpret_cast<const int2*>(col)[t];
        if ((unsigned)c2.x < NNODES) atomicAdd(&cnt[c2.x], 1);
        if ((unsigned)c2.y < NNODES) atomicAdd(&cnt[c2.y], 1);
    }
}

// ======================= CSR scans =======================

__global__ __launch_bounds__(SCAN_BLK) void lgcn_scan1(
    const int* __restrict__ cnt, int* __restrict__ startv, int* __restrict__ bsum)
{
    __shared__ int sh[SCAN_BLK];
    int b = blockIdx.x;
    int base = b * SCAN_CHUNK;
    int tid = threadIdx.x;
    int v[SCAN_ITEMS];
    int local = 0;
    #pragma unroll
    for (int k = 0; k < SCAN_ITEMS; ++k) {
        int idx = base + tid * SCAN_ITEMS + k;
        v[k] = (idx < NNODES) ? cnt[idx] : 0;
        local += v[k];
    }
    sh[tid] = local;
    __syncthreads();
    for (int off = 1; off < SCAN_BLK; off <<= 1) {
        int x = (tid >= off) ? sh[tid - off] : 0;
        __syncthreads();
        sh[tid] += x;
        __syncthreads();
    }
    int run = (tid == 0) ? 0 : sh[tid - 1];
    if (tid == SCAN_BLK - 1) bsum[b] = sh[tid];
    #pragma unroll
    for (int k = 0; k < SCAN_ITEMS; ++k) {
        int idx = base + tid * SCAN_ITEMS + k;
        if (idx < NNODES) startv[idx] = run;
        run += v[k];
    }
}

__global__ __launch_bounds__(SCAN_BLK) void lgcn_scan2(int* __restrict__ bsum)
{
    __shared__ int sh[SCAN_BLK];
    int tid = threadIdx.x;
    sh[tid] = (tid < NB1) ? bsum[tid] : 0;
    __syncthreads();
    for (int off = 1; off < SCAN_BLK; off <<= 1) {
        int x = (tid >= off) ? sh[tid - off] : 0;
        __syncthreads();
        sh[tid] += x;
        __syncthreads();
    }
    if (tid < NB1) bsum[tid] = (tid == 0) ? 0 : sh[tid - 1];
}

__global__ __launch_bounds__(256) void lgcn_scan3(
    int* __restrict__ startv, int* __restrict__ cursor, const int* __restrict__ bsum)
{
    int i = blockIdx.x * blockDim.x + threadIdx.x;
    if (i < NNODES) {
        int s = startv[i] + bsum[i / SCAN_CHUNK];
        startv[i] = s;
        cursor[i] = s;
    }
    if (i == 0) startv[NNODES] = NEDGE;
}

// ============ fill: XCD-class col partition (blockIdx&7 == class) ============
// Blocks of class j scan ALL edges, write only cols in [j*62500,(j+1)*62500).
// Each class's pairs writes land in a contiguous ~1.25 MB region -> fits its
// XCD's 4 MB L2 -> lines fully merge before writeback (kills the 8x write
// amplification). Correct for ANY block->XCD mapping; fast if round-robin.
__global__ __launch_bounds__(256) void lgcn_fill_part(
    const int* __restrict__ row, const int* __restrict__ col,
    const float* __restrict__ w, int* __restrict__ cursor,
    unsigned long long* __restrict__ pairs)
{
    const int cls = blockIdx.x & (FILL_CLASSES - 1);
    const int q   = blockIdx.x >> 3;
    const int lo  = cls * COLS_PER_CLS;
    const int hi  = lo + COLS_PER_CLS;
    const int2* col2 = reinterpret_cast<const int2*>(col);

    for (int t = q * 256 + threadIdx.x; t < NEDGE / 2; t += FILL_BPC * 256) {
        int2 c2 = col2[t];
        if (c2.x >= lo && c2.x < hi) {
            int e = 2 * t;
            int r = row[e]; float wt = w[e];
            if ((unsigned)r >= NNODES) { r = 0; wt = 0.f; }
            int p = atomicAdd(&cursor[c2.x], 1);
            pairs[p] = (unsigned long long)(unsigned)r
                     | ((unsigned long long)__float_as_uint(wt) << 32);
        }
        if (c2.y >= lo && c2.y < hi) {
            int e = 2 * t + 1;
            int r = row[e]; float wt = w[e];
            if ((unsigned)r >= NNODES) { r = 0; wt = 0.f; }
            int p = atomicAdd(&cursor[c2.y], 1);
            pairs[p] = (unsigned long long)(unsigned)r
                     | ((unsigned long long)__float_as_uint(wt) << 32);
        }
    }
}

// ======================= gather: 8 nodes/wave, 8 lanes/node =======================
// Lane sub = 8 consecutive dims (uint4 = 8 bf16 = 16 B). Unconditional clamped
// batch loads keep 8 rows in flight per group (r14-proven structure).
// MODE 0: E16 -> X1 bf16;  MODE 1: X1 -> X2 bf16
// MODE 2: X2 + streams -> out fp32 = 0.25*(emb+X1+X2+G)  (nt streams)
template<int MODE>
__global__ __launch_bounds__(256, 4) void lgcn_gather(
    const unsigned short* __restrict__ src16, unsigned short* __restrict__ xout16,
    const float* __restrict__ emb, const unsigned short* __restrict__ x1,
    const unsigned short* __restrict__ x2, float* __restrict__ outp,
    const int2* __restrict__ pairs, const int* __restrict__ startv)
{
    int t = blockIdx.x * blockDim.x + threadIdx.x;
    int wid = t >> 6;               // wave id: 8 nodes/wave
    int lane = t & 63;
    int g = lane >> 3;              // node slot (0..7)
    int sub = lane & 7;             // dim octet (dims sub*8 .. sub*8+7)
    int n = wid * 8 + g;
    if (n >= NNODES) return;

    int s = startv[n];              // broadcast within 8-lane group
    int e = startv[n + 1];

    float a0=0.f,a1=0.f,a2=0.f,a3=0.f,a4=0.f,a5=0.f,a6=0.f,a7=0.f;

    for (int i = s; i < e; i += 8) {     // empty nodes skip entirely
        int2 pr[8];
        #pragma unroll
        for (int k = 0; k < 8; ++k) {
            int idx = i + k;
            idx = idx < e ? idx : e - 1;     // clamp; e>s here so e-1>=s
            pr[k] = pairs[idx];              // unconditional broadcast load
        }
        uint4 rv[8];
        #pragma unroll
        for (int k = 0; k < 8; ++k) {
            rv[k] = *reinterpret_cast<const uint4*>(
                &src16[(size_t)pr[k].x * DIMV + sub * 8]);   // unconditional
        }
        #pragma unroll
        for (int k = 0; k < 8; ++k) {
            float wk = (i + k < e) ? __int_as_float(pr[k].y) : 0.f;
            a0 = fmaf(wk, bflo(rv[k].x), a0);
            a1 = fmaf(wk, bfhi(rv[k].x), a1);
            a2 = fmaf(wk, bflo(rv[k].y), a2);
            a3 = fmaf(wk, bfhi(rv[k].y), a3);
            a4 = fmaf(wk, bflo(rv[k].z), a4);
            a5 = fmaf(wk, bfhi(rv[k].z), a5);
            a6 = fmaf(wk, bflo(rv[k].w), a6);
            a7 = fmaf(wk, bfhi(rv[k].w), a7);
        }
    }

    const size_t o = (size_t)n * DIMV + sub * 8;
    if (MODE == 2) {
        fx4 e0 = __builtin_nontemporal_load(reinterpret_cast<const fx4*>(&emb[o]));
        fx4 e1 = __builtin_nontemporal_load(reinterpret_cast<const fx4*>(&emb[o + 4]));
        ux4 u1 = __builtin_nontemporal_load(reinterpret_cast<const ux4*>(&x1[o]));
        uint4 u2 = *reinterpret_cast<const uint4*>(&x2[o]);
        fx4 r0, r1;
        r0.x = (e0.x + bflo(u1.x) + bflo(u2.x) + a0) * 0.25f;
        r0.y = (e0.y + bfhi(u1.x) + bfhi(u2.x) + a1) * 0.25f;
        r0.z = (e0.z + bflo(u1.y) + bflo(u2.y) + a2) * 0.25f;
        r0.w = (e0.w + bfhi(u1.y) + bfhi(u2.y) + a3) * 0.25f;
        r1.x = (e1.x + bflo(u1.z) + bflo(u2.z) + a4) * 0.25f;
        r1.y = (e1.y + bfhi(u1.z) + bfhi(u2.z) + a5) * 0.25f;
        r1.z = (e1.z + bflo(u1.w) + bflo(u2.w) + a6) * 0.25f;
        r1.w = (e1.w + bfhi(u1.w) + bfhi(u2.w) + a7) * 0.25f;
        __builtin_nontemporal_store(r0, reinterpret_cast<fx4*>(&outp[o]));
        __builtin_nontemporal_store(r1, reinterpret_cast<fx4*>(&outp[o + 4]));
    } else {
        unsigned long long lo =
              (unsigned long long)((unsigned)f2bf(a0) | ((unsigned)f2bf(a1) << 16))
            | ((unsigned long long)((unsigned)f2bf(a2) | ((unsigned)f2bf(a3) << 16)) << 32);
        unsigned long long hi =
              (unsigned long long)((unsigned)f2bf(a4) | ((unsigned)f2bf(a5) << 16))
            | ((unsigned long long)((unsigned)f2bf(a6) | ((unsigned)f2bf(a7) << 16)) << 32);
        __builtin_nontemporal_store(lo, reinterpret_cast<unsigned long long*>(&xout16[o]));
        __builtin_nontemporal_store(hi, reinterpret_cast<unsigned long long*>(&xout16[o + 4]));
    }
}

// ======================= fallback: atomic scatter path (fp32) =======================

__global__ __launch_bounds__(256) void lgcn_init(
    const float4* __restrict__ emb, float4* __restrict__ acc,
    float4* __restrict__ A, float4* __restrict__ B)
{
    int i = blockIdx.x * blockDim.x + threadIdx.x;
    int stride = gridDim.x * blockDim.x;
    for (; i < NELEM4; i += stride) {
        float4 v = emb[i];
        acc[i] = v;
        A[i]   = v;
        B[i]   = make_float4(0.f, 0.f, 0.f, 0.f);
    }
}

__global__ __launch_bounds__(256) void lgcn_scatter(
    const float* __restrict__ xcur, float* __restrict__ xnext,
    const int* __restrict__ row, const int* __restrict__ col,
    const float* __restrict__ w)
{
    int t = blockIdx.x * blockDim.x + threadIdx.x;
    int e = t >> 4;
    if (e >= NEDGE) return;
    int d = (t & 15) << 2;
    int r = row[e];
    int c = col[e];
    if ((unsigned)r >= NNODES || (unsigned)c >= NNODES) return;
    float wt = w[e];
    const float4 v = *reinterpret_cast<const float4*>(xcur + (size_t)r * DIMV + d);
    float* dst = xnext + (size_t)c * DIMV + d;
    atomicAdd(dst + 0, wt * v.x);
    atomicAdd(dst + 1, wt * v.y);
    atomicAdd(dst + 2, wt * v.z);
    atomicAdd(dst + 3, wt * v.w);
}

__global__ __launch_bounds__(256) void lgcn_addzero(
    float4* __restrict__ acc, const float4* __restrict__ X, float4* __restrict__ Y)
{
    int i = blockIdx.x * blockDim.x + threadIdx.x;
    int stride = gridDim.x * blockDim.x;
    for (; i < NELEM4; i += stride) {
        float4 a = acc[i];
        float4 x = X[i];
        a.x += x.x; a.y += x.y; a.z += x.z; a.w += x.w;
        acc[i] = a;
        Y[i] = make_float4(0.f, 0.f, 0.f, 0.f);
    }
}

__global__ __launch_bounds__(256) void lgcn_final(
    float4* __restrict__ acc, const float4* __restrict__ X)
{
    int i = blockIdx.x * blockDim.x + threadIdx.x;
    int stride = gridDim.x * blockDim.x;
    for (; i < NELEM4; i += stride) {
        float4 a = acc[i];
        float4 x = X[i];
        a.x = (a.x + x.x) * 0.25f;
        a.y = (a.y + x.y) * 0.25f;
        a.z = (a.z + x.z) * 0.25f;
        a.w = (a.w + x.w) * 0.25f;
        acc[i] = a;
    }
}

// ======================= launch =======================

extern "C" void kernel_launch(void* const* d_in, const int* in_sizes, int n_in,
                              void* d_out, int out_size, void* d_ws, size_t ws_size,
                              hipStream_t stream) {
    const float* emb  = (const float*)d_in[0];   // [N, 64] fp32
    const int*   eidx = (const int*)d_in[1];     // [2, E] int32
    const float* ew   = (const float*)d_in[2];   // [E] fp32
    float* acc = (float*)d_out;                  // [N, 64]

    const int* row = eidx;
    const int* col = eidx + NEDGE;

    // workspace: E16, X1, X2 (bf16, 64 MB each) + CSR arrays
    unsigned short* E16 = (unsigned short*)d_ws;         // NELEM*2
    unsigned short* X1  = E16 + NELEM;                   // NELEM*2
    unsigned short* X2  = X1 + NELEM;                    // NELEM*2
    int2*  pairs  = (int2*)(X2 + NELEM);                 // 10e6 B (8-aligned)
    int*   startv = (int*)(pairs + NEDGE);               // (N+1)*4
    int*   cursor = startv + (NNODES + 1);               // N*4
    int*   bsum   = cursor + NNODES;                     // NB1*4
    const size_t needed = (size_t)3 * NELEM * 2 + (size_t)NEDGE * 8
                        + ((size_t)NNODES + 1) * 4 + (size_t)NNODES * 4 + (size_t)NB1 * 4;

    const int NODE_BLOCKS = (NNODES + 255) / 256;
    const int GW_BLOCKS   = (NNODES * 8 + 255) / 256;    // 8 nodes/wave

    if (ws_size >= needed) {
        // ---- CSR counts + bf16 table (fused) ----
        hipMemsetAsync(cursor, 0, (size_t)NNODES * 4, stream);
        lgcn_cvt_hist<<<CVT_BLOCKS + EDGE2_BLOCKS, 256, 0, stream>>>(
            (const float4*)emb, (unsigned long long*)E16, col, cursor);

        // ---- scans + partitioned fill ----
        lgcn_scan1<<<NB1, SCAN_BLK, 0, stream>>>(cursor, startv, bsum);
        lgcn_scan2<<<1, SCAN_BLK, 0, stream>>>(bsum);
        lgcn_scan3<<<NODE_BLOCKS, 256, 0, stream>>>(startv, cursor, bsum);
        lgcn_fill_part<<<FILL_CLASSES * FILL_BPC, 256, 0, stream>>>(
            row, col, ew, cursor, (unsigned long long*)pairs);

        // ---- layers ----
        lgcn_gather<0><<<GW_BLOCKS, 256, 0, stream>>>(
            E16, X1, nullptr, nullptr, nullptr, nullptr, pairs, startv);
        lgcn_gather<1><<<GW_BLOCKS, 256, 0, stream>>>(
            X1, X2, nullptr, nullptr, nullptr, nullptr, pairs, startv);
        lgcn_gather<2><<<GW_BLOCKS, 256, 0, stream>>>(
            X2, nullptr, emb, X1, X2, acc, pairs, startv);
    } else {
        // ---- fallback: proven fp32 atomic-scatter path ----
        float* A = (float*)d_ws;
        float* B = A + NELEM;
        const int SC_BLOCKS = (NEDGE * 16 + 255) / 256;
        lgcn_init<<<2048, 256, 0, stream>>>(
            (const float4*)emb, (float4*)acc, (float4*)A, (float4*)B);
        lgcn_scatter<<<SC_BLOCKS, 256, 0, stream>>>(A, B, row, col, ew);
        lgcn_addzero<<<2048, 256, 0, stream>>>((float4*)acc, (const float4*)B, (float4*)A);
        lgcn_scatter<<<SC_BLOCKS, 256, 0, stream>>>(B, A, row, col, ew);
        lgcn_addzero<<<2048, 256, 0, stream>>>((float4*)acc, (const float4*)A, (float4*)B);
        lgcn_scatter<<<SC_BLOCKS, 256, 0, stream>>>(A, B, row, col, ew);
        lgcn_final<<<2048, 256, 0, stream>>>((float4*)acc, (const float4*)B);
    }
}

// Round 17
// 341.665 us; speedup vs baseline: 3.0598x; 1.0215x over previous
//
#include <hip/hip_runtime.h>

// LightGCN: loop-free cvt (cached stores), hist, XCD-class-partitioned fill,
// 8-nodes/wave bf16 gathers with cache-resident tables.
// E16 = bf16(emb); X1 = G(E16); X2 = G(X1); out = 0.25*(emb+X1+X2+G(X2)).

#define NNODES   500000
#define DIMV     64
#define NEDGE    1250000
#define NELEM    (NNODES * DIMV)          // 32,000,000
#define NELEM4   (NELEM / 4)

#define SCAN_BLK   256
#define SCAN_ITEMS 8
#define SCAN_CHUNK (SCAN_BLK * SCAN_ITEMS)              // 2048
#define NB1 ((NNODES + SCAN_CHUNK - 1) / SCAN_CHUNK)    // 245 (<= 256)

#define EDGE2_BLOCKS ((NEDGE / 2 + 255) / 256)          // 2442

#define FILL_CLASSES  8
#define FILL_BPC      256                                // blocks per class
#define COLS_PER_CLS  (NNODES / FILL_CLASSES)            // 62500

typedef float  fx4 __attribute__((ext_vector_type(4)));

// bf16 helpers (RNE)
static __device__ __forceinline__ unsigned short f2bf(float f) {
    unsigned u = __float_as_uint(f);
    unsigned r = (u + 0x7fffu + ((u >> 16) & 1u)) >> 16;
    return (unsigned short)r;
}
static __device__ __forceinline__ float bflo(unsigned u) {
    return __uint_as_float(u << 16);
}
static __device__ __forceinline__ float bfhi(unsigned u) {
    return __uint_as_float(u & 0xffff0000u);
}

// ============ emb -> bf16 table: loop-free, cached stores ============
__global__ __launch_bounds__(256) void lgcn_cvt(
    const float4* __restrict__ emb4, unsigned long long* __restrict__ dst)
{
    int i = blockIdx.x * 256 + threadIdx.x;   // grid sized exactly: no loop
    float4 v = emb4[i];
    unsigned lo = (unsigned)f2bf(v.x) | ((unsigned)f2bf(v.y) << 16);
    unsigned hi = (unsigned)f2bf(v.z) | ((unsigned)f2bf(v.w) << 16);
    dst[i] = (unsigned long long)lo | ((unsigned long long)hi << 32);  // cached
}

// ============ hist: 2 edges/thread ============
__global__ __launch_bounds__(256) void lgcn_hist(
    const int* __restrict__ col, int* __restrict__ cnt)
{
    int t = blockIdx.x * blockDim.x + threadIdx.x;
    if (t >= NEDGE / 2) return;
    int2 c2 = reinterpret_cast<const int2*>(col)[t];
    if ((unsigned)c2.x < NNODES) atomicAdd(&cnt[c2.x], 1);
    if ((unsigned)c2.y < NNODES) atomicAdd(&cnt[c2.y], 1);
}

// ======================= CSR scans =======================

__global__ __launch_bounds__(SCAN_BLK) void lgcn_scan1(
    const int* __restrict__ cnt, int* __restrict__ startv, int* __restrict__ bsum)
{
    __shared__ int sh[SCAN_BLK];
    int b = blockIdx.x;
    int base = b * SCAN_CHUNK;
    int tid = threadIdx.x;
    int v[SCAN_ITEMS];
    int local = 0;
    #pragma unroll
    for (int k = 0; k < SCAN_ITEMS; ++k) {
        int idx = base + tid * SCAN_ITEMS + k;
        v[k] = (idx < NNODES) ? cnt[idx] : 0;
        local += v[k];
    }
    sh[tid] = local;
    __syncthreads();
    for (int off = 1; off < SCAN_BLK; off <<= 1) {
        int x = (tid >= off) ? sh[tid - off] : 0;
        __syncthreads();
        sh[tid] += x;
        __syncthreads();
    }
    int run = (tid == 0) ? 0 : sh[tid - 1];
    if (tid == SCAN_BLK - 1) bsum[b] = sh[tid];
    #pragma unroll
    for (int k = 0; k < SCAN_ITEMS; ++k) {
        int idx = base + tid * SCAN_ITEMS + k;
        if (idx < NNODES) startv[idx] = run;
        run += v[k];
    }
}

__global__ __launch_bounds__(SCAN_BLK) void lgcn_scan2(int* __restrict__ bsum)
{
    __shared__ int sh[SCAN_BLK];
    int tid = threadIdx.x;
    sh[tid] = (tid < NB1) ? bsum[tid] : 0;
    __syncthreads();
    for (int off = 1; off < SCAN_BLK; off <<= 1) {
        int x = (tid >= off) ? sh[tid - off] : 0;
        __syncthreads();
        sh[tid] += x;
        __syncthreads();
    }
    if (tid < NB1) bsum[tid] = (tid == 0) ? 0 : sh[tid - 1];
}

__global__ __launch_bounds__(256) void lgcn_scan3(
    int* __restrict__ startv, int* __restrict__ cursor, const int* __restrict__ bsum)
{
    int i = blockIdx.x * blockDim.x + threadIdx.x;
    if (i < NNODES) {
        int s = startv[i] + bsum[i / SCAN_CHUNK];
        startv[i] = s;
        cursor[i] = s;
    }
    if (i == 0) startv[NNODES] = NEDGE;
}

// ============ fill: XCD-class col partition (blockIdx&7 == class) ============
__global__ __launch_bounds__(256) void lgcn_fill_part(
    const int* __restrict__ row, const int* __restrict__ col,
    const float* __restrict__ w, int* __restrict__ cursor,
    unsigned long long* __restrict__ pairs)
{
    const int cls = blockIdx.x & (FILL_CLASSES - 1);
    const int q   = blockIdx.x >> 3;
    const int lo  = cls * COLS_PER_CLS;
    const int hi  = lo + COLS_PER_CLS;
    const int2* col2 = reinterpret_cast<const int2*>(col);

    for (int t = q * 256 + threadIdx.x; t < NEDGE / 2; t += FILL_BPC * 256) {
        int2 c2 = col2[t];
        if (c2.x >= lo && c2.x < hi) {
            int e = 2 * t;
            int r = row[e]; float wt = w[e];
            if ((unsigned)r >= NNODES) { r = 0; wt = 0.f; }
            int p = atomicAdd(&cursor[c2.x], 1);
            pairs[p] = (unsigned long long)(unsigned)r
                     | ((unsigned long long)__float_as_uint(wt) << 32);
        }
        if (c2.y >= lo && c2.y < hi) {
            int e = 2 * t + 1;
            int r = row[e]; float wt = w[e];
            if ((unsigned)r >= NNODES) { r = 0; wt = 0.f; }
            int p = atomicAdd(&cursor[c2.y], 1);
            pairs[p] = (unsigned long long)(unsigned)r
                     | ((unsigned long long)__float_as_uint(wt) << 32);
        }
    }
}

// ======================= gather: 8 nodes/wave, 8 lanes/node =======================
// Unconditional clamped batch loads (r14-proven). Table writes CACHED so the
// next gather reads an L2/L3-hot table.
// MODE 0: E16 -> X1;  MODE 1: X1 -> X2;  MODE 2: X2+streams -> out fp32
template<int MODE>
__global__ __launch_bounds__(256, 4) void lgcn_gather(
    const unsigned short* __restrict__ src16, unsigned short* __restrict__ xout16,
    const float* __restrict__ emb, const unsigned short* __restrict__ x1,
    const unsigned short* __restrict__ x2, float* __restrict__ outp,
    const int2* __restrict__ pairs, const int* __restrict__ startv)
{
    int t = blockIdx.x * blockDim.x + threadIdx.x;
    int wid = t >> 6;               // wave id: 8 nodes/wave
    int lane = t & 63;
    int g = lane >> 3;              // node slot (0..7)
    int sub = lane & 7;             // dim octet (dims sub*8 .. sub*8+7)
    int n = wid * 8 + g;
    if (n >= NNODES) return;

    int s = startv[n];              // broadcast within 8-lane group
    int e = startv[n + 1];

    float a0=0.f,a1=0.f,a2=0.f,a3=0.f,a4=0.f,a5=0.f,a6=0.f,a7=0.f;

    for (int i = s; i < e; i += 8) {     // empty nodes skip entirely
        int2 pr[8];
        #pragma unroll
        for (int k = 0; k < 8; ++k) {
            int idx = i + k;
            idx = idx < e ? idx : e - 1;     // clamp; e>s here so e-1>=s
            pr[k] = pairs[idx];              // unconditional broadcast load
        }
        uint4 rv[8];
        #pragma unroll
        for (int k = 0; k < 8; ++k) {
            rv[k] = *reinterpret_cast<const uint4*>(
                &src16[(size_t)pr[k].x * DIMV + sub * 8]);   // unconditional
        }
        #pragma unroll
        for (int k = 0; k < 8; ++k) {
            float wk = (i + k < e) ? __int_as_float(pr[k].y) : 0.f;
            a0 = fmaf(wk, bflo(rv[k].x), a0);
            a1 = fmaf(wk, bfhi(rv[k].x), a1);
            a2 = fmaf(wk, bflo(rv[k].y), a2);
            a3 = fmaf(wk, bfhi(rv[k].y), a3);
            a4 = fmaf(wk, bflo(rv[k].z), a4);
            a5 = fmaf(wk, bfhi(rv[k].z), a5);
            a6 = fmaf(wk, bflo(rv[k].w), a6);
            a7 = fmaf(wk, bfhi(rv[k].w), a7);
        }
    }

    const size_t o = (size_t)n * DIMV + sub * 8;
    if (MODE == 2) {
        fx4 e0 = __builtin_nontemporal_load(reinterpret_cast<const fx4*>(&emb[o]));
        fx4 e1 = __builtin_nontemporal_load(reinterpret_cast<const fx4*>(&emb[o + 4]));
        uint4 u1 = *reinterpret_cast<const uint4*>(&x1[o]);      // cache-hot
        uint4 u2 = *reinterpret_cast<const uint4*>(&x2[o]);      // cache-hot
        fx4 r0, r1;
        r0.x = (e0.x + bflo(u1.x) + bflo(u2.x) + a0) * 0.25f;
        r0.y = (e0.y + bfhi(u1.x) + bfhi(u2.x) + a1) * 0.25f;
        r0.z = (e0.z + bflo(u1.y) + bflo(u2.y) + a2) * 0.25f;
        r0.w = (e0.w + bfhi(u1.y) + bfhi(u2.y) + a3) * 0.25f;
        r1.x = (e1.x + bflo(u1.z) + bflo(u2.z) + a4) * 0.25f;
        r1.y = (e1.y + bfhi(u1.z) + bfhi(u2.z) + a5) * 0.25f;
        r1.z = (e1.z + bflo(u1.w) + bflo(u2.w) + a6) * 0.25f;
        r1.w = (e1.w + bfhi(u1.w) + bfhi(u2.w) + a7) * 0.25f;
        __builtin_nontemporal_store(r0, reinterpret_cast<fx4*>(&outp[o]));
        __builtin_nontemporal_store(r1, reinterpret_cast<fx4*>(&outp[o + 4]));
    } else {
        unsigned long long lo =
              (unsigned long long)((unsigned)f2bf(a0) | ((unsigned)f2bf(a1) << 16))
            | ((unsigned long long)((unsigned)f2bf(a2) | ((unsigned)f2bf(a3) << 16)) << 32);
        unsigned long long hi =
              (unsigned long long)((unsigned)f2bf(a4) | ((unsigned)f2bf(a5) << 16))
            | ((unsigned long long)((unsigned)f2bf(a6) | ((unsigned)f2bf(a7) << 16)) << 32);
        // CACHED stores: this table is the next gather's random-read source
        reinterpret_cast<unsigned long long*>(&xout16[o])[0]    = lo;
        reinterpret_cast<unsigned long long*>(&xout16[o + 4])[0] = hi;
    }
}

// ======================= fallback: atomic scatter path (fp32) =======================

__global__ __launch_bounds__(256) void lgcn_init(
    const float4* __restrict__ emb, float4* __restrict__ acc,
    float4* __restrict__ A, float4* __restrict__ B)
{
    int i = blockIdx.x * blockDim.x + threadIdx.x;
    int stride = gridDim.x * blockDim.x;
    for (; i < NELEM4; i += stride) {
        float4 v = emb[i];
        acc[i] = v;
        A[i]   = v;
        B[i]   = make_float4(0.f, 0.f, 0.f, 0.f);
    }
}

__global__ __launch_bounds__(256) void lgcn_scatter(
    const float* __restrict__ xcur, float* __restrict__ xnext,
    const int* __restrict__ row, const int* __restrict__ col,
    const float* __restrict__ w)
{
    int t = blockIdx.x * blockDim.x + threadIdx.x;
    int e = t >> 4;
    if (e >= NEDGE) return;
    int d = (t & 15) << 2;
    int r = row[e];
    int c = col[e];
    if ((unsigned)r >= NNODES || (unsigned)c >= NNODES) return;
    float wt = w[e];
    const float4 v = *reinterpret_cast<const float4*>(xcur + (size_t)r * DIMV + d);
    float* dst = xnext + (size_t)c * DIMV + d;
    atomicAdd(dst + 0, wt * v.x);
    atomicAdd(dst + 1, wt * v.y);
    atomicAdd(dst + 2, wt * v.z);
    atomicAdd(dst + 3, wt * v.w);
}

__global__ __launch_bounds__(256) void lgcn_addzero(
    float4* __restrict__ acc, const float4* __restrict__ X, float4* __restrict__ Y)
{
    int i = blockIdx.x * blockDim.x + threadIdx.x;
    int stride = gridDim.x * blockDim.x;
    for (; i < NELEM4; i += stride) {
        float4 a = acc[i];
        float4 x = X[i];
        a.x += x.x; a.y += x.y; a.z += x.z; a.w += x.w;
        acc[i] = a;
        Y[i] = make_float4(0.f, 0.f, 0.f, 0.f);
    }
}

__global__ __launch_bounds__(256) void lgcn_final(
    float4* __restrict__ acc, const float4* __restrict__ X)
{
    int i = blockIdx.x * blockDim.x + threadIdx.x;
    int stride = gridDim.x * blockDim.x;
    for (; i < NELEM4; i += stride) {
        float4 a = acc[i];
        float4 x = X[i];
        a.x = (a.x + x.x) * 0.25f;
        a.y = (a.y + x.y) * 0.25f;
        a.z = (a.z + x.z) * 0.25f;
        a.w = (a.w + x.w) * 0.25f;
        acc[i] = a;
    }
}

// ======================= launch =======================

extern "C" void kernel_launch(void* const* d_in, const int* in_sizes, int n_in,
                              void* d_out, int out_size, void* d_ws, size_t ws_size,
                              hipStream_t stream) {
    const float* emb  = (const float*)d_in[0];   // [N, 64] fp32
    const int*   eidx = (const int*)d_in[1];     // [2, E] int32
    const float* ew   = (const float*)d_in[2];   // [E] fp32
    float* acc = (float*)d_out;                  // [N, 64]

    const int* row = eidx;
    const int* col = eidx + NEDGE;

    // workspace: E16, X1, X2 (bf16, 64 MB each) + CSR arrays
    unsigned short* E16 = (unsigned short*)d_ws;         // NELEM*2
    unsigned short* X1  = E16 + NELEM;                   // NELEM*2
    unsigned short* X2  = X1 + NELEM;                    // NELEM*2
    int2*  pairs  = (int2*)(X2 + NELEM);                 // 10e6 B (8-aligned)
    int*   startv = (int*)(pairs + NEDGE);               // (N+1)*4
    int*   cursor = startv + (NNODES + 1);               // N*4
    int*   bsum   = cursor + NNODES;                     // NB1*4
    const size_t needed = (size_t)3 * NELEM * 2 + (size_t)NEDGE * 8
                        + ((size_t)NNODES + 1) * 4 + (size_t)NNODES * 4 + (size_t)NB1 * 4;

    const int NODE_BLOCKS = (NNODES + 255) / 256;
    const int GW_BLOCKS   = (NNODES * 8 + 255) / 256;    // 8 nodes/wave
    const int CVT_BLOCKS2 = NELEM4 / 256;                // 32768, loop-free

    if (ws_size >= needed) {
        // ---- CSR counts + bf16 table ----
        hipMemsetAsync(cursor, 0, (size_t)NNODES * 4, stream);
        lgcn_cvt<<<CVT_BLOCKS2, 256, 0, stream>>>(
            (const float4*)emb, (unsigned long long*)E16);
        lgcn_hist<<<EDGE2_BLOCKS, 256, 0, stream>>>(col, cursor);

        // ---- scans + partitioned fill ----
        lgcn_scan1<<<NB1, SCAN_BLK, 0, stream>>>(cursor, startv, bsum);
        lgcn_scan2<<<1, SCAN_BLK, 0, stream>>>(bsum);
        lgcn_scan3<<<NODE_BLOCKS, 256, 0, stream>>>(startv, cursor, bsum);
        lgcn_fill_part<<<FILL_CLASSES * FILL_BPC, 256, 0, stream>>>(
            row, col, ew, cursor, (unsigned long long*)pairs);

        // ---- layers ----
        lgcn_gather<0><<<GW_BLOCKS, 256, 0, stream>>>(
            E16, X1, nullptr, nullptr, nullptr, nullptr, pairs, startv);
        lgcn_gather<1><<<GW_BLOCKS, 256, 0, stream>>>(
            X1, X2, nullptr, nullptr, nullptr, nullptr, pairs, startv);
        lgcn_gather<2><<<GW_BLOCKS, 256, 0, stream>>>(
            X2, nullptr, emb, X1, X2, acc, pairs, startv);
    } else {
        // ---- fallback: proven fp32 atomic-scatter path ----
        float* A = (float*)d_ws;
        float* B = A + NELEM;
        const int SC_BLOCKS = (NEDGE * 16 + 255) / 256;
        lgcn_init<<<2048, 256, 0, stream>>>(
            (const float4*)emb, (float4*)acc, (float4*)A, (float4*)B);
        lgcn_scatter<<<SC_BLOCKS, 256, 0, stream>>>(A, B, row, col, ew);
        lgcn_addzero<<<2048, 256, 0, stream>>>((float4*)acc, (const float4*)B, (float4*)A);
        lgcn_scatter<<<SC_BLOCKS, 256, 0, stream>>>(B, A, row, col, ew);
        lgcn_addzero<<<2048, 256, 0, stream>>>((float4*)acc, (const float4*)A, (float4*)B);
        lgcn_scatter<<<SC_BLOCKS, 256, 0, stream>>>(A, B, row, col, ew);
        lgcn_final<<<2048, 256, 0, stream>>>((float4*)acc, (const float4*)B);
    }
}

// Round 18
// 335.123 us; speedup vs baseline: 3.1195x; 1.0195x over previous
//
#include <hip/hip_runtime.h>

// LightGCN: fused loop-free cvt + hist, XCD-class-partitioned fill,
// 8-nodes/wave bf16 gathers with cache-resident tables.
// E16 = bf16(emb); X1 = G(E16); X2 = G(X1); out = 0.25*(emb+X1+X2+G(X2)).

#define NNODES   500000
#define DIMV     64
#define NEDGE    1250000
#define NELEM    (NNODES * DIMV)          // 32,000,000
#define NELEM4   (NELEM / 4)

#define SCAN_BLK   256
#define SCAN_ITEMS 8
#define SCAN_CHUNK (SCAN_BLK * SCAN_ITEMS)              // 2048
#define NB1 ((NNODES + SCAN_CHUNK - 1) / SCAN_CHUNK)    // 245 (<= 256)

#define CVT_BLOCKS   (NELEM4 / 256)                     // 32768, loop-free
#define EDGE2_BLOCKS ((NEDGE / 2 + 255) / 256)          // 2442

#define FILL_CLASSES  8
#define FILL_BPC      256                                // blocks per class
#define COLS_PER_CLS  (NNODES / FILL_CLASSES)            // 62500

typedef float  fx4 __attribute__((ext_vector_type(4)));

// bf16 helpers (RNE)
static __device__ __forceinline__ unsigned short f2bf(float f) {
    unsigned u = __float_as_uint(f);
    unsigned r = (u + 0x7fffu + ((u >> 16) & 1u)) >> 16;
    return (unsigned short)r;
}
static __device__ __forceinline__ float bflo(unsigned u) {
    return __uint_as_float(u << 16);
}
static __device__ __forceinline__ float bfhi(unsigned u) {
    return __uint_as_float(u & 0xffff0000u);
}

// ====== fused: loop-free emb->bf16 cvt (blocks [0,CVT)) + hist (rest) ======
__global__ __launch_bounds__(256) void lgcn_cvt_hist(
    const float4* __restrict__ emb4, unsigned long long* __restrict__ dst,
    const int* __restrict__ col, int* __restrict__ cnt)
{
    if (blockIdx.x < CVT_BLOCKS) {
        int i = blockIdx.x * 256 + threadIdx.x;       // exactly one elt/thread
        float4 v = emb4[i];
        unsigned lo = (unsigned)f2bf(v.x) | ((unsigned)f2bf(v.y) << 16);
        unsigned hi = (unsigned)f2bf(v.z) | ((unsigned)f2bf(v.w) << 16);
        dst[i] = (unsigned long long)lo | ((unsigned long long)hi << 32); // cached
    } else {
        int t = (blockIdx.x - CVT_BLOCKS) * 256 + threadIdx.x;
        if (t >= NEDGE / 2) return;
        int2 c2 = reinterpret_cast<const int2*>(col)[t];
        if ((unsigned)c2.x < NNODES) atomicAdd(&cnt[c2.x], 1);
        if ((unsigned)c2.y < NNODES) atomicAdd(&cnt[c2.y], 1);
    }
}

// ======================= CSR scans =======================

__global__ __launch_bounds__(SCAN_BLK) void lgcn_scan1(
    const int* __restrict__ cnt, int* __restrict__ startv, int* __restrict__ bsum)
{
    __shared__ int sh[SCAN_BLK];
    int b = blockIdx.x;
    int base = b * SCAN_CHUNK;
    int tid = threadIdx.x;
    int v[SCAN_ITEMS];
    int local = 0;
    #pragma unroll
    for (int k = 0; k < SCAN_ITEMS; ++k) {
        int idx = base + tid * SCAN_ITEMS + k;
        v[k] = (idx < NNODES) ? cnt[idx] : 0;
        local += v[k];
    }
    sh[tid] = local;
    __syncthreads();
    for (int off = 1; off < SCAN_BLK; off <<= 1) {
        int x = (tid >= off) ? sh[tid - off] : 0;
        __syncthreads();
        sh[tid] += x;
        __syncthreads();
    }
    int run = (tid == 0) ? 0 : sh[tid - 1];
    if (tid == SCAN_BLK - 1) bsum[b] = sh[tid];
    #pragma unroll
    for (int k = 0; k < SCAN_ITEMS; ++k) {
        int idx = base + tid * SCAN_ITEMS + k;
        if (idx < NNODES) startv[idx] = run;
        run += v[k];
    }
}

__global__ __launch_bounds__(SCAN_BLK) void lgcn_scan2(int* __restrict__ bsum)
{
    __shared__ int sh[SCAN_BLK];
    int tid = threadIdx.x;
    sh[tid] = (tid < NB1) ? bsum[tid] : 0;
    __syncthreads();
    for (int off = 1; off < SCAN_BLK; off <<= 1) {
        int x = (tid >= off) ? sh[tid - off] : 0;
        __syncthreads();
        sh[tid] += x;
        __syncthreads();
    }
    if (tid < NB1) bsum[tid] = (tid == 0) ? 0 : sh[tid - 1];
}

__global__ __launch_bounds__(256) void lgcn_scan3(
    int* __restrict__ startv, int* __restrict__ cursor, const int* __restrict__ bsum)
{
    int i = blockIdx.x * blockDim.x + threadIdx.x;
    if (i < NNODES) {
        int s = startv[i] + bsum[i / SCAN_CHUNK];
        startv[i] = s;
        cursor[i] = s;
    }
    if (i == 0) startv[NNODES] = NEDGE;
}

// ============ fill: XCD-class col partition (blockIdx&7 == class) ============
__global__ __launch_bounds__(256) void lgcn_fill_part(
    const int* __restrict__ row, const int* __restrict__ col,
    const float* __restrict__ w, int* __restrict__ cursor,
    unsigned long long* __restrict__ pairs)
{
    const int cls = blockIdx.x & (FILL_CLASSES - 1);
    const int q   = blockIdx.x >> 3;
    const int lo  = cls * COLS_PER_CLS;
    const int hi  = lo + COLS_PER_CLS;
    const int2* col2 = reinterpret_cast<const int2*>(col);

    for (int t = q * 256 + threadIdx.x; t < NEDGE / 2; t += FILL_BPC * 256) {
        int2 c2 = col2[t];
        if (c2.x >= lo && c2.x < hi) {
            int e = 2 * t;
            int r = row[e]; float wt = w[e];
            if ((unsigned)r >= NNODES) { r = 0; wt = 0.f; }
            int p = atomicAdd(&cursor[c2.x], 1);
            pairs[p] = (unsigned long long)(unsigned)r
                     | ((unsigned long long)__float_as_uint(wt) << 32);
        }
        if (c2.y >= lo && c2.y < hi) {
            int e = 2 * t + 1;
            int r = row[e]; float wt = w[e];
            if ((unsigned)r >= NNODES) { r = 0; wt = 0.f; }
            int p = atomicAdd(&cursor[c2.y], 1);
            pairs[p] = (unsigned long long)(unsigned)r
                     | ((unsigned long long)__float_as_uint(wt) << 32);
        }
    }
}

// ======================= gather: 8 nodes/wave, 8 lanes/node =======================
// Unconditional clamped batch loads (r14-proven). Table writes CACHED so the
// next gather reads an L2/L3-hot table.
// MODE 0: E16 -> X1;  MODE 1: X1 -> X2;  MODE 2: X2+streams -> out fp32
template<int MODE>
__global__ __launch_bounds__(256, 4) void lgcn_gather(
    const unsigned short* __restrict__ src16, unsigned short* __restrict__ xout16,
    const float* __restrict__ emb, const unsigned short* __restrict__ x1,
    const unsigned short* __restrict__ x2, float* __restrict__ outp,
    const int2* __restrict__ pairs, const int* __restrict__ startv)
{
    int t = blockIdx.x * blockDim.x + threadIdx.x;
    int wid = t >> 6;               // wave id: 8 nodes/wave
    int lane = t & 63;
    int g = lane >> 3;              // node slot (0..7)
    int sub = lane & 7;             // dim octet (dims sub*8 .. sub*8+7)
    int n = wid * 8 + g;
    if (n >= NNODES) return;

    int s = startv[n];              // broadcast within 8-lane group
    int e = startv[n + 1];

    float a0=0.f,a1=0.f,a2=0.f,a3=0.f,a4=0.f,a5=0.f,a6=0.f,a7=0.f;

    for (int i = s; i < e; i += 8) {     // empty nodes skip entirely
        int2 pr[8];
        #pragma unroll
        for (int k = 0; k < 8; ++k) {
            int idx = i + k;
            idx = idx < e ? idx : e - 1;     // clamp; e>s here so e-1>=s
            pr[k] = pairs[idx];              // unconditional broadcast load
        }
        uint4 rv[8];
        #pragma unroll
        for (int k = 0; k < 8; ++k) {
            rv[k] = *reinterpret_cast<const uint4*>(
                &src16[(size_t)pr[k].x * DIMV + sub * 8]);   // unconditional
        }
        #pragma unroll
        for (int k = 0; k < 8; ++k) {
            float wk = (i + k < e) ? __int_as_float(pr[k].y) : 0.f;
            a0 = fmaf(wk, bflo(rv[k].x), a0);
            a1 = fmaf(wk, bfhi(rv[k].x), a1);
            a2 = fmaf(wk, bflo(rv[k].y), a2);
            a3 = fmaf(wk, bfhi(rv[k].y), a3);
            a4 = fmaf(wk, bflo(rv[k].z), a4);
            a5 = fmaf(wk, bfhi(rv[k].z), a5);
            a6 = fmaf(wk, bflo(rv[k].w), a6);
            a7 = fmaf(wk, bfhi(rv[k].w), a7);
        }
    }

    const size_t o = (size_t)n * DIMV + sub * 8;
    if (MODE == 2) {
        fx4 e0 = __builtin_nontemporal_load(reinterpret_cast<const fx4*>(&emb[o]));
        fx4 e1 = __builtin_nontemporal_load(reinterpret_cast<const fx4*>(&emb[o + 4]));
        uint4 u1 = *reinterpret_cast<const uint4*>(&x1[o]);      // cache-hot
        uint4 u2 = *reinterpret_cast<const uint4*>(&x2[o]);      // cache-hot
        fx4 r0, r1;
        r0.x = (e0.x + bflo(u1.x) + bflo(u2.x) + a0) * 0.25f;
        r0.y = (e0.y + bfhi(u1.x) + bfhi(u2.x) + a1) * 0.25f;
        r0.z = (e0.z + bflo(u1.y) + bflo(u2.y) + a2) * 0.25f;
        r0.w = (e0.w + bfhi(u1.y) + bfhi(u2.y) + a3) * 0.25f;
        r1.x = (e1.x + bflo(u1.z) + bflo(u2.z) + a4) * 0.25f;
        r1.y = (e1.y + bfhi(u1.z) + bfhi(u2.z) + a5) * 0.25f;
        r1.z = (e1.z + bflo(u1.w) + bflo(u2.w) + a6) * 0.25f;
        r1.w = (e1.w + bfhi(u1.w) + bfhi(u2.w) + a7) * 0.25f;
        __builtin_nontemporal_store(r0, reinterpret_cast<fx4*>(&outp[o]));
        __builtin_nontemporal_store(r1, reinterpret_cast<fx4*>(&outp[o + 4]));
    } else {
        unsigned long long lo =
              (unsigned long long)((unsigned)f2bf(a0) | ((unsigned)f2bf(a1) << 16))
            | ((unsigned long long)((unsigned)f2bf(a2) | ((unsigned)f2bf(a3) << 16)) << 32);
        unsigned long long hi =
              (unsigned long long)((unsigned)f2bf(a4) | ((unsigned)f2bf(a5) << 16))
            | ((unsigned long long)((unsigned)f2bf(a6) | ((unsigned)f2bf(a7) << 16)) << 32);
        // CACHED stores: this table is the next gather's random-read source
        reinterpret_cast<unsigned long long*>(&xout16[o])[0]    = lo;
        reinterpret_cast<unsigned long long*>(&xout16[o + 4])[0] = hi;
    }
}

// ======================= fallback: atomic scatter path (fp32) =======================

__global__ __launch_bounds__(256) void lgcn_init(
    const float4* __restrict__ emb, float4* __restrict__ acc,
    float4* __restrict__ A, float4* __restrict__ B)
{
    int i = blockIdx.x * blockDim.x + threadIdx.x;
    int stride = gridDim.x * blockDim.x;
    for (; i < NELEM4; i += stride) {
        float4 v = emb[i];
        acc[i] = v;
        A[i]   = v;
        B[i]   = make_float4(0.f, 0.f, 0.f, 0.f);
    }
}

__global__ __launch_bounds__(256) void lgcn_scatter(
    const float* __restrict__ xcur, float* __restrict__ xnext,
    const int* __restrict__ row, const int* __restrict__ col,
    const float* __restrict__ w)
{
    int t = blockIdx.x * blockDim.x + threadIdx.x;
    int e = t >> 4;
    if (e >= NEDGE) return;
    int d = (t & 15) << 2;
    int r = row[e];
    int c = col[e];
    if ((unsigned)r >= NNODES || (unsigned)c >= NNODES) return;
    float wt = w[e];
    const float4 v = *reinterpret_cast<const float4*>(xcur + (size_t)r * DIMV + d);
    float* dst = xnext + (size_t)c * DIMV + d;
    atomicAdd(dst + 0, wt * v.x);
    atomicAdd(dst + 1, wt * v.y);
    atomicAdd(dst + 2, wt * v.z);
    atomicAdd(dst + 3, wt * v.w);
}

__global__ __launch_bounds__(256) void lgcn_addzero(
    float4* __restrict__ acc, const float4* __restrict__ X, float4* __restrict__ Y)
{
    int i = blockIdx.x * blockDim.x + threadIdx.x;
    int stride = gridDim.x * blockDim.x;
    for (; i < NELEM4; i += stride) {
        float4 a = acc[i];
        float4 x = X[i];
        a.x += x.x; a.y += x.y; a.z += x.z; a.w += x.w;
        acc[i] = a;
        Y[i] = make_float4(0.f, 0.f, 0.f, 0.f);
    }
}

__global__ __launch_bounds__(256) void lgcn_final(
    float4* __restrict__ acc, const float4* __restrict__ X)
{
    int i = blockIdx.x * blockDim.x + threadIdx.x;
    int stride = gridDim.x * blockDim.x;
    for (; i < NELEM4; i += stride) {
        float4 a = acc[i];
        float4 x = X[i];
        a.x = (a.x + x.x) * 0.25f;
        a.y = (a.y + x.y) * 0.25f;
        a.z = (a.z + x.z) * 0.25f;
        a.w = (a.w + x.w) * 0.25f;
        acc[i] = a;
    }
}

// ======================= launch =======================

extern "C" void kernel_launch(void* const* d_in, const int* in_sizes, int n_in,
                              void* d_out, int out_size, void* d_ws, size_t ws_size,
                              hipStream_t stream) {
    const float* emb  = (const float*)d_in[0];   // [N, 64] fp32
    const int*   eidx = (const int*)d_in[1];     // [2, E] int32
    const float* ew   = (const float*)d_in[2];   // [E] fp32
    float* acc = (float*)d_out;                  // [N, 64]

    const int* row = eidx;
    const int* col = eidx + NEDGE;

    // workspace: E16, X1, X2 (bf16, 64 MB each) + CSR arrays
    unsigned short* E16 = (unsigned short*)d_ws;         // NELEM*2
    unsigned short* X1  = E16 + NELEM;                   // NELEM*2
    unsigned short* X2  = X1 + NELEM;                    // NELEM*2
    int2*  pairs  = (int2*)(X2 + NELEM);                 // 10e6 B (8-aligned)
    int*   startv = (int*)(pairs + NEDGE);               // (N+1)*4
    int*   cursor = startv + (NNODES + 1);               // N*4
    int*   bsum   = cursor + NNODES;                     // NB1*4
    const size_t needed = (size_t)3 * NELEM * 2 + (size_t)NEDGE * 8
                        + ((size_t)NNODES + 1) * 4 + (size_t)NNODES * 4 + (size_t)NB1 * 4;

    const int NODE_BLOCKS = (NNODES + 255) / 256;
    const int GW_BLOCKS   = (NNODES * 8 + 255) / 256;    // 8 nodes/wave

    if (ws_size >= needed) {
        // ---- fused bf16 table + CSR counts ----
        hipMemsetAsync(cursor, 0, (size_t)NNODES * 4, stream);
        lgcn_cvt_hist<<<CVT_BLOCKS + EDGE2_BLOCKS, 256, 0, stream>>>(
            (const float4*)emb, (unsigned long long*)E16, col, cursor);

        // ---- scans + partitioned fill ----
        lgcn_scan1<<<NB1, SCAN_BLK, 0, stream>>>(cursor, startv, bsum);
        lgcn_scan2<<<1, SCAN_BLK, 0, stream>>>(bsum);
        lgcn_scan3<<<NODE_BLOCKS, 256, 0, stream>>>(startv, cursor, bsum);
        lgcn_fill_part<<<FILL_CLASSES * FILL_BPC, 256, 0, stream>>>(
            row, col, ew, cursor, (unsigned long long*)pairs);

        // ---- layers ----
        lgcn_gather<0><<<GW_BLOCKS, 256, 0, stream>>>(
            E16, X1, nullptr, nullptr, nullptr, nullptr, pairs, startv);
        lgcn_gather<1><<<GW_BLOCKS, 256, 0, stream>>>(
            X1, X2, nullptr, nullptr, nullptr, nullptr, pairs, startv);
        lgcn_gather<2><<<GW_BLOCKS, 256, 0, stream>>>(
            X2, nullptr, emb, X1, X2, acc, pairs, startv);
    } else {
        // ---- fallback: proven fp32 atomic-scatter path ----
        float* A = (float*)d_ws;
        float* B = A + NELEM;
        const int SC_BLOCKS = (NEDGE * 16 + 255) / 256;
        lgcn_init<<<2048, 256, 0, stream>>>(
            (const float4*)emb, (float4*)acc, (float4*)A, (float4*)B);
        lgcn_scatter<<<SC_BLOCKS, 256, 0, stream>>>(A, B, row, col, ew);
        lgcn_addzero<<<2048, 256, 0, stream>>>((float4*)acc, (const float4*)B, (float4*)A);
        lgcn_scatter<<<SC_BLOCKS, 256, 0, stream>>>(B, A, row, col, ew);
        lgcn_addzero<<<2048, 256, 0, stream>>>((float4*)acc, (const float4*)A, (float4*)B);
        lgcn_scatter<<<SC_BLOCKS, 256, 0, stream>>>(A, B, row, col, ew);
        lgcn_final<<<2048, 256, 0, stream>>>((float4*)acc, (const float4*)B);
    }
}